// Round 12
// baseline (1660.030 us; speedup 1.0000x reference)
//
#include <hip/hip_runtime.h>

#define HID 2048
#define INTER 1408
#define NEXP 14
#define SINTER 2816
#define TTOK 2048

#define GLU_SH 88    // 22 nt x 4 m-slices (512 rows each)
#define GLU_RT 154   // 14 e x 11 nt (in-block m-loop)
#define DWN_SH 64    // 16 nt x 4 m-slices (512 rows)
#define DWN_RT 224   // 14 e x 16 nt (in-block m-loop)

#define STG 49152    // bytes per pipeline stage (3-deep ring)

typedef short bf16x8 __attribute__((ext_vector_type(8)));
typedef float f32x4 __attribute__((ext_vector_type(4)));
typedef unsigned short u16x8 __attribute__((ext_vector_type(8)));

__device__ __forceinline__ unsigned short f2bf(float f) {
    __bf16 b = (__bf16)f;
    return __builtin_bit_cast(unsigned short, b);
}
__device__ __forceinline__ float bf2f(unsigned short u) {
    unsigned v = (unsigned)u << 16;
    return __builtin_bit_cast(float, v);
}
__device__ __forceinline__ unsigned swz256(unsigned b) { return b ^ (((b >> 8) & 7u) << 4); }
__device__ __forceinline__ bf16x8 pk8(float4 a, float4 b) {
    bf16x8 v;
    v[0] = (short)f2bf(a.x); v[1] = (short)f2bf(a.y);
    v[2] = (short)f2bf(a.z); v[3] = (short)f2bf(a.w);
    v[4] = (short)f2bf(b.x); v[5] = (short)f2bf(b.y);
    v[6] = (short)f2bf(b.z); v[7] = (short)f2bf(b.w);
    return v;
}

__device__ __forceinline__ void gload16(const void* g, void* l) {
    __builtin_amdgcn_global_load_lds((__attribute__((address_space(1))) void*)g,
                                     (__attribute__((address_space(3))) void*)l, 16, 0, 0);
}
__device__ __forceinline__ void bsync() {
    __builtin_amdgcn_sched_barrier(0);
    __builtin_amdgcn_s_barrier();
    __builtin_amdgcn_sched_barrier(0);
}
#define WAIT_VM_(n) asm volatile("s_waitcnt vmcnt(" #n ")" ::: "memory")
#define WAIT_VM(n) WAIT_VM_(n)
#define FENCE __builtin_amdgcn_sched_barrier(0)
#define MFMA16(a, b, c) __builtin_amdgcn_mfma_f32_16x16x32_bf16(a, b, c, 0, 0, 0)

__global__ void k_zero(int* cnt) {
    if ((int)threadIdx.x < NEXP) cnt[threadIdx.x] = 0;
}

// fp32 -> bf16 stream conversion (x only)
__global__ __launch_bounds__(256) void k_w2b(const float* __restrict__ src,
                                             unsigned short* __restrict__ dst, int n8) {
    int stride = gridDim.x * 256;
    for (int i = blockIdx.x * 256 + threadIdx.x; i < n8; i += stride) {
        size_t o = (size_t)i * 8;
        float4 a = *(const float4*)(src + o);
        float4 b = *(const float4*)(src + o + 4);
        u16x8 v;
        v[0] = f2bf(a.x); v[1] = f2bf(a.y); v[2] = f2bf(a.z); v[3] = f2bf(a.w);
        v[4] = f2bf(b.x); v[5] = f2bf(b.y); v[6] = f2bf(b.z); v[7] = f2bf(b.w);
        *(u16x8*)(dst + o) = v;
    }
}

// Router, vectorized (R11-proven).
__global__ __launch_bounds__(256, 4) void k_router(
    const float* __restrict__ x,
    const float* __restrict__ gate_w, const float* __restrict__ cls_w,
    const float* __restrict__ escale, const float* __restrict__ ebias,
    int* __restrict__ cnt, int* __restrict__ etok, float* __restrict__ ew) {
    const int lane = threadIdx.x & 63;
    const int tok = blockIdx.x * 4 + (threadIdx.x >> 6);
    const float* xr = x + (size_t)tok * HID + lane * 4;
    float4 xv[8];
#pragma unroll
    for (int i = 0; i < 8; i++) xv[i] = *(const float4*)(xr + i * 256);

    float sc[NEXP];
    float mx = 0.f;
#pragma unroll
    for (int e = 0; e < NEXP; e++) {
        const float* cw = cls_w + (size_t)e * HID + lane * 4;
        const float* gw = gate_w + (size_t)e * HID + lane * 4;
        float pc = 0.f, pg = 0.f;
        {
            float4 cv[8];
#pragma unroll
            for (int i = 0; i < 8; i++) cv[i] = *(const float4*)(cw + i * 256);
#pragma unroll
            for (int i = 0; i < 8; i++) {
                pc = fmaf(xv[i].x, cv[i].x, pc);
                pc = fmaf(xv[i].y, cv[i].y, pc);
                pc = fmaf(xv[i].z, cv[i].z, pc);
                pc = fmaf(xv[i].w, cv[i].w, pc);
            }
        }
        {
            float4 gv[8];
#pragma unroll
            for (int i = 0; i < 8; i++) gv[i] = *(const float4*)(gw + i * 256);
#pragma unroll
            for (int i = 0; i < 8; i++) {
                pg = fmaf(xv[i].x, gv[i].x, pg);
                pg = fmaf(xv[i].y, gv[i].y, pg);
                pg = fmaf(xv[i].z, gv[i].z, pg);
                pg = fmaf(xv[i].w, gv[i].w, pg);
            }
        }
#pragma unroll
        for (int o = 32; o >= 1; o >>= 1) {
            pc += __shfl_xor(pc, o);
            pg += __shfl_xor(pg, o);
        }
        float lg = pc * (pg / (1.f + __expf(-pg)));
        sc[e] = fabsf(lg);
        mx = fmaxf(mx, sc[e]);
    }
    float s = 0.f;
#pragma unroll
    for (int e = 0; e < NEXP; e++) { sc[e] = __expf(sc[e] - mx); s += sc[e]; }
    float inv = 1.f / s;
    int i1 = -1, i2 = -1;
    float b1 = -1e30f, b2 = -1e30f, v1 = 0.f, v2 = 0.f;
#pragma unroll
    for (int e = 0; e < NEXP; e++) {
        float sv = sc[e] * inv;
        float b = sv + ebias[e];
        if (b > b1) { b2 = b1; i2 = i1; v2 = v1; b1 = b; i1 = e; v1 = sv; }
        else if (b > b2) { b2 = b; i2 = e; v2 = sv; }
    }
    if (lane == 0) {
        float w1 = 1.f + v1 * escale[i1];
        float w2 = 1.f + v2 * escale[i2];
        int p1 = atomicAdd(&cnt[i1], 1);
        etok[i1 * TTOK + p1] = tok * 2;     ew[i1 * TTOK + p1] = w1;
        int p2 = atomicAdd(&cnt[i2], 1);
        etok[i2 * TTOK + p2] = tok * 2 + 1; ew[i2 * TTOK + p2] = w2;
    }
}

__global__ void k_offsets(const int* __restrict__ cnt, int* __restrict__ offs) {
    if (threadIdx.x == 0) {
        int a = 0;
        for (int e = 0; e < NEXP; e++) { offs[e] = a; a += cnt[e]; }
    }
}

// Gate+up GEMM. BM=256, BN=128(G)+128(U), BK=32, 3-stage DMA ring.
// A: bf16 DMA. B: fp32 DMA, bf16 convert at fragment load. 1024 thr / 16 waves (8m x 2n).
__global__ __launch_bounds__(1024, 4) void k_glu12(
    const unsigned short* __restrict__ xb,
    const float* __restrict__ wg, const float* __restrict__ wu,
    const float* __restrict__ sg, const float* __restrict__ su,
    unsigned short* __restrict__ abuf, unsigned short* __restrict__ hbuf,
    const int* __restrict__ cnt, const int* __restrict__ offs,
    const int* __restrict__ etok) {
    __shared__ char smem[3 * STG];   // per stage: A 16K | Bg 16K(fp32) | Bu 16K(fp32)

    const int bx = blockIdx.x, t = threadIdx.x;
    const int lane = t & 63, w = t >> 6;
    const int wm = w >> 1, wn = w & 1;
    const int fr = lane & 15, fo = lane >> 4;

    const bool routed = bx >= GLU_SH;
    int n0, m_start, m_stop, obase, Ntot;
    const float *Bg, *Bu;
    unsigned short* outp;
    const int* etk = nullptr;
    if (routed) {
        int rx = bx - GLU_SH;
        int e = rx / 11; n0 = (rx % 11) * 128;
        int M = cnt[e];
        if (M <= 0) return;
        m_start = 0; m_stop = M; obase = offs[e]; Ntot = INTER;
        Bg = wg + ((size_t)e * INTER + n0) * HID;
        Bu = wu + ((size_t)e * INTER + n0) * HID;
        outp = abuf; etk = etok + e * TTOK;
    } else {
        n0 = (bx >> 2) * 128;
        m_start = (bx & 3) * 512; m_stop = m_start + 512;
        obase = 0; Ntot = SINTER;
        Bg = sg + (size_t)n0 * HID;
        Bu = su + (size_t)n0 * HID;
        outp = hbuf;
    }

    // A stage: wave w rows w*16+(lane>>2), chunk(16B)=lane&3, src pre-swizzled
    const int arow = lane >> 2;
    const int achk = (lane & 3) ^ (arow & 3);
    // B stage: wave w rows w*8+(lane>>3), chunk(16B)=lane&7, pair-preserving swizzle
    const int brow = lane >> 3;
    const int bchk = (lane & 7) ^ ((brow & 3) << 1);
    const float* srcG = Bg + (size_t)(w * 8 + brow) * HID + bchk * 4;
    const float* srcU = Bu + (size_t)(w * 8 + brow) * HID + bchk * 4;

    // fragment offsets
    unsigned aoff[2], boff[4];
#pragma unroll
    for (int mi = 0; mi < 2; mi++) {
        int r = wm * 32 + mi * 16 + fr;
        aoff[mi] = (unsigned)(r * 64 + ((fo ^ (r & 3)) << 4));
    }
#pragma unroll
    for (int nj = 0; nj < 4; nj++) {
        int c = wn * 64 + nj * 16 + fr;
        boff[nj] = (unsigned)(c * 128 + (((2 * fo) ^ ((c & 3) << 1)) << 4));
    }

    for (int m0 = m_start; m0 < m_stop; m0 += 256) {
        const int rv = min(m_stop - m0, 256);
        const bool aV = (w * 16) < rv;
        const unsigned short* srcA;
        {
            int r = w * 16 + arow;
            int rr = r < rv ? r : rv - 1;
            int tok = routed ? (etk[m0 + rr] >> 1) : (m0 + rr);
            srcA = xb + (size_t)tok * HID + achk * 8;
        }

        f32x4 ag[2][4], au[2][4];
#pragma unroll
        for (int mi = 0; mi < 2; mi++)
#pragma unroll
            for (int nj = 0; nj < 4; nj++) { ag[mi][nj] = {0.f,0.f,0.f,0.f}; au[mi][nj] = {0.f,0.f,0.f,0.f}; }

        auto issue = [&](int kt, char* buf) {
            if (aV) gload16(srcA + kt * 32, buf + w * 1024);
            gload16(srcG + kt * 32, buf + 16384 + w * 1024);
            gload16(srcU + kt * 32, buf + 32768 + w * 1024);
        };

        // prologue: tiles 0,1,2 -> stages 0,1,2
        issue(0, smem);
        issue(1, smem + STG);
        issue(2, smem + 2 * STG);

        int cur = 0;
        for (int kk = 0; kk < 64; ++kk) {
            if (kk + 2 < 64)      { if (aV) { WAIT_VM(6); } else { WAIT_VM(4); } }
            else if (kk + 1 < 64) { if (aV) { WAIT_VM(3); } else { WAIT_VM(2); } }
            else                  { WAIT_VM(0); }
            FENCE;
            bsync();                                // tile kk valid in stage cur
            {
                const char* base = smem + cur * STG;
                bf16x8 af0 = *(const bf16x8*)(base + aoff[0]);
                bf16x8 af1 = *(const bf16x8*)(base + aoff[1]);
#pragma unroll
                for (int nj = 0; nj < 4; nj++) {
                    float4 g0 = *(const float4*)(base + 16384 + boff[nj]);
                    float4 g1 = *(const float4*)(base + 16384 + boff[nj] + 16);
                    bf16x8 gf = pk8(g0, g1);
                    ag[0][nj] = MFMA16(af0, gf, ag[0][nj]);
                    ag[1][nj] = MFMA16(af1, gf, ag[1][nj]);
                    float4 u0 = *(const float4*)(base + 32768 + boff[nj]);
                    float4 u1 = *(const float4*)(base + 32768 + boff[nj] + 16);
                    bf16x8 uf = pk8(u0, u1);
                    au[0][nj] = MFMA16(af0, uf, au[0][nj]);
                    au[1][nj] = MFMA16(af1, uf, au[1][nj]);
                }
            }
            bsync();                                // all waves done reading stage cur
            if (kk + 3 < 64) issue(kk + 3, smem + cur * STG);
            cur = cur + 1; if (cur == 3) cur = 0;
        }

        // epilogue: h = silu(g)*u -> stage bf16 [256][128] -> coalesced sweep
        char* sH = smem;
#pragma unroll
        for (int mi = 0; mi < 2; mi++)
#pragma unroll
            for (int jj = 0; jj < 4; jj++) {
                int r = wm * 32 + mi * 16 + fo * 4 + jj;
#pragma unroll
                for (int nj = 0; nj < 4; nj++) {
                    int c = wn * 64 + nj * 16 + fr;
                    float g = ag[mi][nj][jj];
                    float u = au[mi][nj][jj];
                    float h = (g / (1.f + __expf(-g))) * u;
                    *(unsigned short*)(sH + swz256((unsigned)(r * 256 + c * 2))) = f2bf(h);
                }
            }
        asm volatile("s_waitcnt lgkmcnt(0)" ::: "memory");
        bsync();
#pragma unroll
        for (int q = 0; q < 4; q++) {
            int idx = q * 1024 + t;
            int r = idx >> 4, c16 = idx & 15;
            if (r < rv) {
                uint4 v = *(const uint4*)(sH + swz256((unsigned)(r * 256 + c16 * 16)));
                *(uint4*)(outp + (size_t)(obase + m0 + r) * Ntot + n0 + c16 * 8) = v;
            }
        }
        bsync();
    }
}

// Down GEMM. BM=512, BN=128, BK=32, 3-stage DMA ring. A bf16 DMA, B fp32 DMA + cvt.
__global__ __launch_bounds__(1024, 4) void k_down12(
    const unsigned short* __restrict__ abuf, const unsigned short* __restrict__ hbuf,
    const float* __restrict__ wd, const float* __restrict__ sd,
    unsigned short* __restrict__ slots,
    const int* __restrict__ cnt, const int* __restrict__ offs,
    const int* __restrict__ etok, const float* __restrict__ ew) {
    __shared__ char smem[3 * STG];   // per stage: A 32K | B 16K(fp32)

    const int bx = blockIdx.x, t = threadIdx.x;
    const int lane = t & 63, w = t >> 6;
    const int wm = w >> 1, wn = w & 1;
    const int fr = lane & 15, fo = lane >> 4;

    const bool routed = bx >= DWN_SH;
    int n0, m_start, m_stop, K, KT;
    const float* W;
    const unsigned short* Abuf;
    size_t arow0 = 0;
    const int* etk = nullptr; const float* ewe = nullptr;
    if (routed) {
        int rx = bx - DWN_SH;
        int e = rx / 16; n0 = (rx % 16) * 128;
        int M = cnt[e];
        if (M <= 0) return;
        m_start = 0; m_stop = M;
        K = INTER; KT = INTER / 32;
        W = wd + (size_t)e * HID * INTER + (size_t)n0 * INTER;
        Abuf = abuf; arow0 = offs[e];
        etk = etok + e * TTOK; ewe = ew + e * TTOK;
    } else {
        n0 = (bx >> 2) * 128;
        m_start = (bx & 3) * 512; m_stop = m_start + 512;
        K = SINTER; KT = SINTER / 32;
        W = sd + (size_t)n0 * SINTER;
        Abuf = hbuf;
    }

    const int arow = lane >> 2;
    const int achk = (lane & 3) ^ (arow & 3);
    const int brow = lane >> 3;
    const int bchk = (lane & 7) ^ ((brow & 3) << 1);
    const float* srcB = W + (size_t)(w * 8 + brow) * K + bchk * 4;

    unsigned aoff[4], boff[4];
#pragma unroll
    for (int mi = 0; mi < 4; mi++) {
        int r = wm * 64 + mi * 16 + fr;
        aoff[mi] = (unsigned)(r * 64 + ((fo ^ (r & 3)) << 4));
    }
#pragma unroll
    for (int nj = 0; nj < 4; nj++) {
        int c = wn * 64 + nj * 16 + fr;
        boff[nj] = (unsigned)(c * 128 + (((2 * fo) ^ ((c & 3) << 1)) << 4));
    }

    for (int m0 = m_start; m0 < m_stop; m0 += 512) {
        const int rv = min(m_stop - m0, 512);
        const bool aV = (w * 32) < rv;
        const unsigned short* srcA0;
        const unsigned short* srcA1;
        {
            int r0 = w * 32 + arow;
            int r1 = w * 32 + 16 + arow;
            int rr0 = r0 < rv ? r0 : rv - 1;
            int rr1 = r1 < rv ? r1 : rv - 1;
            srcA0 = Abuf + (arow0 + m0 + rr0) * (size_t)K + achk * 8;
            srcA1 = Abuf + (arow0 + m0 + rr1) * (size_t)K + achk * 8;
        }

        f32x4 ac[4][4];
#pragma unroll
        for (int mi = 0; mi < 4; mi++)
#pragma unroll
            for (int nj = 0; nj < 4; nj++) ac[mi][nj] = {0.f, 0.f, 0.f, 0.f};

        auto issue = [&](int kt, char* buf) {
            if (aV) {
                gload16(srcA0 + kt * 32, buf + w * 2048);
                gload16(srcA1 + kt * 32, buf + w * 2048 + 1024);
            }
            gload16(srcB + kt * 32, buf + 32768 + w * 1024);
        };

        issue(0, smem);
        if (1 < KT) issue(1, smem + STG);
        if (2 < KT) issue(2, smem + 2 * STG);

        int cur = 0;
        for (int kk = 0; kk < KT; ++kk) {
            if (kk + 2 < KT)      { if (aV) { WAIT_VM(6); } else { WAIT_VM(2); } }
            else if (kk + 1 < KT) { if (aV) { WAIT_VM(3); } else { WAIT_VM(1); } }
            else                  { WAIT_VM(0); }
            FENCE;
            bsync();
            {
                const char* base = smem + cur * STG;
                bf16x8 af[4];
#pragma unroll
                for (int mi = 0; mi < 4; mi++) af[mi] = *(const bf16x8*)(base + aoff[mi]);
#pragma unroll
                for (int nj = 0; nj < 4; nj++) {
                    float4 b0 = *(const float4*)(base + 32768 + boff[nj]);
                    float4 b1 = *(const float4*)(base + 32768 + boff[nj] + 16);
                    bf16x8 bf = pk8(b0, b1);
#pragma unroll
                    for (int mi = 0; mi < 4; mi++)
                        ac[mi][nj] = MFMA16(af[mi], bf, ac[mi][nj]);
                }
            }
            bsync();
            if (kk + 3 < KT) issue(kk + 3, smem + cur * STG);
            cur = cur + 1; if (cur == 3) cur = 0;
        }

        // epilogue: scale, stage bf16 [512][128], sweep to slot slices
        char* sH = smem;
#pragma unroll
        for (int mi = 0; mi < 4; mi++)
#pragma unroll
            for (int jj = 0; jj < 4; jj++) {
                int r = wm * 64 + mi * 16 + fo * 4 + jj;
                float wt = 1.f;
                if (routed) wt = (r < rv) ? ewe[m0 + r] : 0.f;
#pragma unroll
                for (int nj = 0; nj < 4; nj++) {
                    int c = wn * 64 + nj * 16 + fr;
                    *(unsigned short*)(sH + swz256((unsigned)(r * 256 + c * 2))) =
                        f2bf(ac[mi][nj][jj] * wt);
                }
            }
        asm volatile("s_waitcnt lgkmcnt(0)" ::: "memory");
        bsync();
#pragma unroll
        for (int q = 0; q < 8; q++) {
            int idx = q * 1024 + t;
            int r = idx >> 4, c16 = idx & 15;
            if (r < rv) {
                uint4 v = *(const uint4*)(sH + swz256((unsigned)(r * 256 + c16 * 16)));
                int tok, slice;
                if (routed) { int entry = etk[m0 + r]; tok = entry >> 1; slice = entry & 1; }
                else        { tok = m0 + r; slice = 2; }
                *(uint4*)(slots + ((size_t)slice * TTOK + tok) * HID + n0 + c16 * 8) = v;
            }
        }
        bsync();
    }
}

__global__ __launch_bounds__(256) void k_final(float* __restrict__ out,
                                               const unsigned short* __restrict__ slots) {
    size_t i = ((size_t)blockIdx.x * 256 + threadIdx.x) * 8;
    u16x8 s0 = *(const u16x8*)(slots + i);
    u16x8 s1 = *(const u16x8*)(slots + (size_t)TTOK * HID + i);
    u16x8 s2 = *(const u16x8*)(slots + (size_t)2 * TTOK * HID + i);
    float4 o0, o1;
    o0.x = bf2f(s0[0]) + bf2f(s1[0]) + bf2f(s2[0]);
    o0.y = bf2f(s0[1]) + bf2f(s1[1]) + bf2f(s2[1]);
    o0.z = bf2f(s0[2]) + bf2f(s1[2]) + bf2f(s2[2]);
    o0.w = bf2f(s0[3]) + bf2f(s1[3]) + bf2f(s2[3]);
    o1.x = bf2f(s0[4]) + bf2f(s1[4]) + bf2f(s2[4]);
    o1.y = bf2f(s0[5]) + bf2f(s1[5]) + bf2f(s2[5]);
    o1.z = bf2f(s0[6]) + bf2f(s1[6]) + bf2f(s2[6]);
    o1.w = bf2f(s0[7]) + bf2f(s1[7]) + bf2f(s2[7]);
    *(float4*)(out + i) = o0;
    *(float4*)(out + i + 4) = o1;
}

extern "C" void kernel_launch(void* const* d_in, const int* in_sizes, int n_in,
                              void* d_out, int out_size, void* d_ws, size_t ws_size,
                              hipStream_t stream) {
    const float* x = (const float*)d_in[0];
    const float* gate_w = (const float*)d_in[1];
    const float* cls_w = (const float*)d_in[2];
    const float* escale = (const float*)d_in[3];
    const float* ebias = (const float*)d_in[4];
    const float* wg = (const float*)d_in[5];
    const float* wu = (const float*)d_in[6];
    const float* wd = (const float*)d_in[7];
    const float* sg = (const float*)d_in[8];
    const float* su = (const float*)d_in[9];
    const float* sd = (const float*)d_in[10];
    float* out = (float*)d_out;

    char* ws = (char*)d_ws;
    size_t o = 0;
    auto alloc = [&](size_t bytes) {
        char* p = ws + o;
        o += (bytes + 255) & ~(size_t)255;
        return p;
    };
    unsigned short* xb    = (unsigned short*)alloc((size_t)TTOK * HID * 2);
    unsigned short* hbuf  = (unsigned short*)alloc((size_t)TTOK * SINTER * 2);
    unsigned short* abuf  = (unsigned short*)alloc((size_t)2 * TTOK * INTER * 2);
    unsigned short* slots = (unsigned short*)alloc((size_t)3 * TTOK * HID * 2);
    int* cnt              = (int*)alloc(256);
    int* offs             = (int*)alloc(256);
    int* etok             = (int*)alloc((size_t)NEXP * TTOK * 4);
    float* ew             = (float*)alloc((size_t)NEXP * TTOK * 4);

    k_zero<<<1, 64, 0, stream>>>(cnt);
    k_w2b<<<2048, 256, 0, stream>>>(x, xb, (int)((size_t)TTOK * HID / 8));
    k_router<<<512, 256, 0, stream>>>(x, gate_w, cls_w, escale, ebias, cnt, etok, ew);
    k_offsets<<<1, 64, 0, stream>>>(cnt, offs);
    k_glu12<<<GLU_SH + GLU_RT, 1024, 0, stream>>>(
        xb, wg, wu, sg, su, abuf, hbuf, cnt, offs, etok);
    k_down12<<<DWN_SH + DWN_RT, 1024, 0, stream>>>(
        abuf, hbuf, wd, sd, slots, cnt, offs, etok, ew);
    k_final<<<2048, 256, 0, stream>>>(out, slots);
}

// Round 13
// 661.444 us; speedup vs baseline: 2.5097x; 2.5097x over previous
//
#include <hip/hip_runtime.h>

#define HID 2048
#define INTER 1408
#define NEXP 14
#define SINTER 2816
#define TTOK 2048
#define BM 256
#define BK 64

#define GLU_SH 88    // 22 nt x 4 m-slices (shared)
#define GLU_RT 154   // 14 e x 11 nt
#define DWN_SH 128   // 8 nt x 16 m-slices (one BM=128 tile each), scheduled first
#define DWN_RT 112   // 14 e x 8 nt (in-block m-loop)
#define DSTG 49152   // down stage: A 16K | B 32K

typedef short bf16x8 __attribute__((ext_vector_type(8)));
typedef float f32x4 __attribute__((ext_vector_type(4)));
typedef unsigned short u16x8 __attribute__((ext_vector_type(8)));

__device__ __forceinline__ unsigned short f2bf(float f) {
    __bf16 b = (__bf16)f;
    return __builtin_bit_cast(unsigned short, b);
}
__device__ __forceinline__ float bf2f(unsigned short u) {
    unsigned v = (unsigned)u << 16;
    return __builtin_bit_cast(float, v);
}
// proven conflict-free swizzles: 128B rows (K-tiles), 256B rows, 512B rows (epilogues)
__device__ __forceinline__ unsigned swz(unsigned b)    { return b ^ (((b >> 7) & 7u) << 4); }
__device__ __forceinline__ unsigned swz256(unsigned b) { return b ^ (((b >> 8) & 7u) << 4); }
__device__ __forceinline__ unsigned swz512(unsigned b) { return b ^ (((b >> 9) & 7u) << 4); }

__device__ __forceinline__ void gload16(const void* g, void* l) {
    __builtin_amdgcn_global_load_lds((__attribute__((address_space(1))) void*)g,
                                     (__attribute__((address_space(3))) void*)l, 16, 0, 0);
}
__device__ __forceinline__ void bsync() {
    __builtin_amdgcn_sched_barrier(0);
    __builtin_amdgcn_s_barrier();
    __builtin_amdgcn_sched_barrier(0);
}
#define WAIT_VM_(n) asm volatile("s_waitcnt vmcnt(" #n ")" ::: "memory")
#define WAIT_VM(n) WAIT_VM_(n)
#define WAIT_LGKM0 asm volatile("s_waitcnt lgkmcnt(0)" ::: "memory")
#define FENCE __builtin_amdgcn_sched_barrier(0)
#define MFMA16(a, b, c) __builtin_amdgcn_mfma_f32_16x16x32_bf16(a, b, c, 0, 0, 0)

__global__ void k_zero(int* cnt) {
    if ((int)threadIdx.x < NEXP) cnt[threadIdx.x] = 0;
}

// fp32 -> bf16 stream conversion (weights)
__global__ __launch_bounds__(256) void k_w2b(const float* __restrict__ src,
                                             unsigned short* __restrict__ dst, int n8) {
    int stride = gridDim.x * 256;
    for (int i = blockIdx.x * 256 + threadIdx.x; i < n8; i += stride) {
        size_t o = (size_t)i * 8;
        float4 a = *(const float4*)(src + o);
        float4 b = *(const float4*)(src + o + 4);
        u16x8 v;
        v[0] = f2bf(a.x); v[1] = f2bf(a.y); v[2] = f2bf(a.z); v[3] = f2bf(a.w);
        v[4] = f2bf(b.x); v[5] = f2bf(b.y); v[6] = f2bf(b.z); v[7] = f2bf(b.w);
        *(u16x8*)(dst + o) = v;
    }
}

// Router, vectorized (R11-proven) + fused x->bf16 store.
__global__ __launch_bounds__(256, 4) void k_router(
    const float* __restrict__ x,
    const float* __restrict__ gate_w, const float* __restrict__ cls_w,
    const float* __restrict__ escale, const float* __restrict__ ebias,
    int* __restrict__ cnt, int* __restrict__ etok, float* __restrict__ ew,
    unsigned short* __restrict__ xb) {
    const int lane = threadIdx.x & 63;
    const int tok = blockIdx.x * 4 + (threadIdx.x >> 6);
    const float* xr = x + (size_t)tok * HID + lane * 4;
    float4 xv[8];
#pragma unroll
    for (int i = 0; i < 8; i++) xv[i] = *(const float4*)(xr + i * 256);
    // bf16 copy of x (coalesced 512B per i)
    unsigned short* xbr = xb + (size_t)tok * HID + lane * 4;
#pragma unroll
    for (int i = 0; i < 8; i++) {
        ushort4 v;
        v.x = f2bf(xv[i].x); v.y = f2bf(xv[i].y);
        v.z = f2bf(xv[i].z); v.w = f2bf(xv[i].w);
        *(ushort4*)(xbr + i * 256) = v;
    }

    float sc[NEXP];
    float mx = 0.f;
#pragma unroll
    for (int e = 0; e < NEXP; e++) {
        const float* cw = cls_w + (size_t)e * HID + lane * 4;
        const float* gw = gate_w + (size_t)e * HID + lane * 4;
        float pc = 0.f, pg = 0.f;
        {
            float4 cv[8];
#pragma unroll
            for (int i = 0; i < 8; i++) cv[i] = *(const float4*)(cw + i * 256);
#pragma unroll
            for (int i = 0; i < 8; i++) {
                pc = fmaf(xv[i].x, cv[i].x, pc);
                pc = fmaf(xv[i].y, cv[i].y, pc);
                pc = fmaf(xv[i].z, cv[i].z, pc);
                pc = fmaf(xv[i].w, cv[i].w, pc);
            }
        }
        {
            float4 gv[8];
#pragma unroll
            for (int i = 0; i < 8; i++) gv[i] = *(const float4*)(gw + i * 256);
#pragma unroll
            for (int i = 0; i < 8; i++) {
                pg = fmaf(xv[i].x, gv[i].x, pg);
                pg = fmaf(xv[i].y, gv[i].y, pg);
                pg = fmaf(xv[i].z, gv[i].z, pg);
                pg = fmaf(xv[i].w, gv[i].w, pg);
            }
        }
#pragma unroll
        for (int o = 32; o >= 1; o >>= 1) {
            pc += __shfl_xor(pc, o);
            pg += __shfl_xor(pg, o);
        }
        float lg = pc * (pg / (1.f + __expf(-pg)));
        sc[e] = fabsf(lg);
        mx = fmaxf(mx, sc[e]);
    }
    float s = 0.f;
#pragma unroll
    for (int e = 0; e < NEXP; e++) { sc[e] = __expf(sc[e] - mx); s += sc[e]; }
    float inv = 1.f / s;
    int i1 = -1, i2 = -1;
    float b1 = -1e30f, b2 = -1e30f, v1 = 0.f, v2 = 0.f;
#pragma unroll
    for (int e = 0; e < NEXP; e++) {
        float sv = sc[e] * inv;
        float b = sv + ebias[e];
        if (b > b1) { b2 = b1; i2 = i1; v2 = v1; b1 = b; i1 = e; v1 = sv; }
        else if (b > b2) { b2 = b; i2 = e; v2 = sv; }
    }
    if (lane == 0) {
        float w1 = 1.f + v1 * escale[i1];
        float w2 = 1.f + v2 * escale[i2];
        int p1 = atomicAdd(&cnt[i1], 1);
        etok[i1 * TTOK + p1] = tok * 2;     ew[i1 * TTOK + p1] = w1;
        int p2 = atomicAdd(&cnt[i2], 1);
        etok[i2 * TTOK + p2] = tok * 2 + 1; ew[i2 * TTOK + p2] = w2;
    }
}

__global__ void k_offsets(const int* __restrict__ cnt, int* __restrict__ offs) {
    if (threadIdx.x == 0) {
        int a = 0;
        for (int e = 0; e < NEXP; e++) { offs[e] = a; a += cnt[e]; }
    }
}

// Gate+up GEMM, pure-DMA (R11-proven). BM=256, BN=128(G)+128(U), BK=64, 1024 thr.
__global__ __launch_bounds__(1024, 4) void k_glu10(
    const unsigned short* __restrict__ xb,
    const unsigned short* __restrict__ wgb, const unsigned short* __restrict__ wub,
    const unsigned short* __restrict__ sgb, const unsigned short* __restrict__ sub,
    unsigned short* __restrict__ abuf, unsigned short* __restrict__ hbuf,
    const int* __restrict__ cnt, const int* __restrict__ offs,
    const int* __restrict__ etok) {
    __shared__ alignas(16) unsigned short sA[2][BM * BK];
    __shared__ alignas(16) unsigned short sBg[2][128 * BK];
    __shared__ alignas(16) unsigned short sBu[2][128 * BK];

    const int bx = blockIdx.x, t = threadIdx.x;
    const int lane = t & 63, w = t >> 6;
    const int wm = w >> 1, wn = w & 1;
    const int fr = lane & 15, fo = lane >> 4;

    const bool routed = bx >= GLU_SH;
    int n0, m_start, m_stop, obase, Ntot;
    const unsigned short *Bg, *Bu;
    unsigned short* outp;
    const int* etk = nullptr;
    if (routed) {
        int rx = bx - GLU_SH;
        int e = rx / 11; n0 = (rx % 11) * 128;
        int M = cnt[e];
        if (M <= 0) return;
        m_start = 0; m_stop = M; obase = offs[e]; Ntot = INTER;
        Bg = wgb + ((size_t)e * INTER + n0) * HID;
        Bu = wub + ((size_t)e * INTER + n0) * HID;
        outp = abuf; etk = etok + e * TTOK;
    } else {
        n0 = (bx >> 2) * 128;
        m_start = (bx & 3) * 512; m_stop = m_start + 512;
        obase = 0; Ntot = SINTER;
        Bg = sgb + (size_t)n0 * HID;
        Bu = sub + (size_t)n0 * HID;
        outp = hbuf;
    }

    const int browo = lane >> 3;
    const int achunk = (lane & 7) ^ browo;
    const unsigned short* srcBg = Bg + (size_t)(w * 8 + browo) * HID + achunk * 8;
    const unsigned short* srcBu = Bu + (size_t)(w * 8 + browo) * HID + achunk * 8;

    unsigned aoff[2][2], boff[4][2];
#pragma unroll
    for (int mi = 0; mi < 2; mi++)
#pragma unroll
        for (int ks = 0; ks < 2; ks++)
            aoff[mi][ks] = swz((unsigned)((wm * 32 + mi * 16 + fr) * 128 + ks * 64 + fo * 16));
#pragma unroll
    for (int nj = 0; nj < 4; nj++)
#pragma unroll
        for (int ks = 0; ks < 2; ks++)
            boff[nj][ks] = swz((unsigned)((wn * 64 + nj * 16 + fr) * 128 + ks * 64 + fo * 16));

    for (int m0 = m_start; m0 < m_stop; m0 += BM) {
        const int rv = min(m_stop - m0, BM);
        const unsigned short* srcA[2];
#pragma unroll
        for (int j = 0; j < 2; j++) {
            int r = w * 16 + j * 8 + browo;
            int rr = r < rv ? r : rv - 1;
            int tok = routed ? (etk[m0 + rr] >> 1) : (m0 + rr);
            srcA[j] = xb + (size_t)tok * HID + achunk * 8;
        }

        f32x4 ag[2][4], au[2][4];
#pragma unroll
        for (int mi = 0; mi < 2; mi++)
#pragma unroll
            for (int nj = 0; nj < 4; nj++) { ag[mi][nj] = {0.f,0.f,0.f,0.f}; au[mi][nj] = {0.f,0.f,0.f,0.f}; }

#pragma unroll
        for (int j = 0; j < 2; j++)
            gload16(srcA[j], (char*)sA[0] + w * 2048 + j * 1024);
        gload16(srcBg, (char*)sBg[0] + w * 1024);
        gload16(srcBu, (char*)sBu[0] + w * 1024);

        for (int kk = 0; kk < HID / BK; ++kk) {
            const int cur = kk & 1;
            bsync();
            if (kk + 1 < HID / BK) {
                const int k1 = (kk + 1) * BK;
#pragma unroll
                for (int j = 0; j < 2; j++)
                    gload16(srcA[j] + k1, (char*)sA[cur ^ 1] + w * 2048 + j * 1024);
                gload16(srcBg + k1, (char*)sBg[cur ^ 1] + w * 1024);
                gload16(srcBu + k1, (char*)sBu[cur ^ 1] + w * 1024);
                FENCE; WAIT_VM(4); FENCE;
            } else {
                FENCE; WAIT_VM(0); FENCE;
            }
            bsync();
#pragma unroll
            for (int ks = 0; ks < 2; ++ks) {
                bf16x8 af[2], gf[4], uf[4];
#pragma unroll
                for (int mi = 0; mi < 2; mi++) af[mi] = *(const bf16x8*)((const char*)sA[cur] + aoff[mi][ks]);
#pragma unroll
                for (int nj = 0; nj < 4; nj++) {
                    gf[nj] = *(const bf16x8*)((const char*)sBg[cur] + boff[nj][ks]);
                    uf[nj] = *(const bf16x8*)((const char*)sBu[cur] + boff[nj][ks]);
                }
#pragma unroll
                for (int mi = 0; mi < 2; mi++)
#pragma unroll
                    for (int nj = 0; nj < 4; nj++) {
                        ag[mi][nj] = MFMA16(af[mi], gf[nj], ag[mi][nj]);
                        au[mi][nj] = MFMA16(af[mi], uf[nj], au[mi][nj]);
                    }
            }
        }

        bsync();
        char* sH = (char*)sA;
#pragma unroll
        for (int mi = 0; mi < 2; mi++)
#pragma unroll
            for (int jj = 0; jj < 4; jj++) {
                int r = wm * 32 + mi * 16 + fo * 4 + jj;
#pragma unroll
                for (int nj = 0; nj < 4; nj++) {
                    int c = wn * 64 + nj * 16 + fr;
                    float g = ag[mi][nj][jj];
                    float u = au[mi][nj][jj];
                    float h = (g / (1.f + __expf(-g))) * u;
                    *(unsigned short*)(sH + swz256((unsigned)(r * 256 + c * 2))) = f2bf(h);
                }
            }
        WAIT_LGKM0;
        bsync();
#pragma unroll
        for (int q = 0; q < 4; q++) {
            int idx = q * 1024 + t;
            int r = idx >> 4, c16 = idx & 15;
            if (r < rv) {
                uint4 v = *(const uint4*)(sH + swz256((unsigned)(r * 256 + c16 * 16)));
                *(uint4*)(outp + (size_t)(obase + m0 + r) * Ntot + n0 + c16 * 8) = v;
            }
        }
        bsync();
    }
}

// Down GEMM. BM=128, BN=256, BK=64, 3-stage DMA ring, 1024 thr / 16 waves (4m x 4n).
__global__ __launch_bounds__(1024, 4) void k_down13(
    const unsigned short* __restrict__ abuf, const unsigned short* __restrict__ hbuf,
    const unsigned short* __restrict__ wdb, const unsigned short* __restrict__ sdb,
    unsigned short* __restrict__ slots,
    const int* __restrict__ cnt, const int* __restrict__ offs,
    const int* __restrict__ etok, const float* __restrict__ ew) {
    __shared__ alignas(16) char smem[3 * DSTG];   // per stage: A 16K | B 32K

    const int bx = blockIdx.x, t = threadIdx.x;
    const int lane = t & 63, w = t >> 6;
    const int wm = w >> 2, wn = w & 3;
    const int fr = lane & 15, fo = lane >> 4;

    const bool routed = bx >= DWN_SH;
    int n0, m_start, m_stop, K, KT;
    const unsigned short* W;
    const unsigned short* Abuf;
    size_t arow0 = 0;
    const int* etk = nullptr; const float* ewe = nullptr;
    if (routed) {
        int rx = bx - DWN_SH;
        int e = rx >> 3; n0 = (rx & 7) * 256;
        int M = cnt[e];
        if (M <= 0) return;
        m_start = 0; m_stop = M;
        K = INTER; KT = INTER / BK;     // 22
        W = wdb + (size_t)e * HID * INTER + (size_t)n0 * INTER;
        Abuf = abuf; arow0 = offs[e];
        etk = etok + e * TTOK; ewe = ew + e * TTOK;
    } else {
        n0 = (bx >> 4) * 256;
        m_start = (bx & 15) * 128; m_stop = m_start + 128;
        K = SINTER; KT = SINTER / BK;   // 44
        W = sdb + (size_t)n0 * SINTER;
        Abuf = hbuf;
    }

    const int rofs = lane >> 3;                 // 0..7
    const int chk = (lane & 7) ^ rofs;          // pre-swizzled source chunk
    // B: 256 rows x 128B; wave w stages rows w*16..+15 (two 8-row issues)
    const unsigned short* srcB0 = W + (size_t)(w * 16 + rofs) * K + chk * 8;
    const unsigned short* srcB1 = W + (size_t)(w * 16 + 8 + rofs) * K + chk * 8;

    unsigned aoff[2][2], boff[4][2];
#pragma unroll
    for (int mi = 0; mi < 2; mi++)
#pragma unroll
        for (int ks = 0; ks < 2; ks++)
            aoff[mi][ks] = swz((unsigned)((wm * 32 + mi * 16 + fr) * 128 + ks * 64 + fo * 16));
#pragma unroll
    for (int nj = 0; nj < 4; nj++)
#pragma unroll
        for (int ks = 0; ks < 2; ks++)
            boff[nj][ks] = 16384u + swz((unsigned)((wn * 64 + nj * 16 + fr) * 128 + ks * 64 + fo * 16));

    for (int m0 = m_start; m0 < m_stop; m0 += 128) {
        const int rv = min(m_stop - m0, 128);
        const unsigned short* srcA;
        {
            int r = w * 8 + rofs;
            int rr = r < rv ? r : rv - 1;
            srcA = Abuf + (arow0 + m0 + rr) * (size_t)K + chk * 8;
        }

        f32x4 ac[2][4];
#pragma unroll
        for (int mi = 0; mi < 2; mi++)
#pragma unroll
            for (int nj = 0; nj < 4; nj++) ac[mi][nj] = {0.f, 0.f, 0.f, 0.f};

        auto issue = [&](int kt, char* buf) {
            gload16(srcA + kt * BK, buf + w * 1024);
            gload16(srcB0 + kt * BK, buf + 16384 + w * 2048);
            gload16(srcB1 + kt * BK, buf + 16384 + w * 2048 + 1024);
        };

        // prologue: 3 stages in flight
        issue(0, smem);
        issue(1, smem + DSTG);
        issue(2, smem + 2 * DSTG);

        int cur = 0;
        for (int kk = 0; kk < KT; ++kk) {
            if (kk < KT - 2)      { FENCE; WAIT_VM(6); FENCE; }
            else if (kk == KT - 2){ FENCE; WAIT_VM(3); FENCE; }
            else                  { FENCE; WAIT_VM(0); FENCE; }
            bsync();                                // stage kk visible
            const char* base = smem + cur * DSTG;
#pragma unroll
            for (int ks = 0; ks < 2; ++ks) {
                bf16x8 af[2], bf[4];
#pragma unroll
                for (int mi = 0; mi < 2; mi++) af[mi] = *(const bf16x8*)(base + aoff[mi][ks]);
#pragma unroll
                for (int nj = 0; nj < 4; nj++) bf[nj] = *(const bf16x8*)(base + boff[nj][ks]);
#pragma unroll
                for (int mi = 0; mi < 2; mi++)
#pragma unroll
                    for (int nj = 0; nj < 4; nj++)
                        ac[mi][nj] = MFMA16(af[mi], bf[nj], ac[mi][nj]);
            }
            bsync();                                // all waves done with stage cur
            if (kk + 3 < KT) issue(kk + 3, smem + cur * DSTG);
            cur = (cur == 2) ? 0 : cur + 1;
        }

        // epilogue: scale, stage bf16 [128][256] (64 KB over stages 0-1), sweep
        char* sH = smem;
#pragma unroll
        for (int mi = 0; mi < 2; mi++)
#pragma unroll
            for (int jj = 0; jj < 4; jj++) {
                int r = wm * 32 + mi * 16 + fo * 4 + jj;
                float wt = 1.f;
                if (routed) wt = (r < rv) ? ewe[m0 + r] : 0.f;
#pragma unroll
                for (int nj = 0; nj < 4; nj++) {
                    int c = wn * 64 + nj * 16 + fr;
                    *(unsigned short*)(sH + swz512((unsigned)(r * 512 + c * 2))) =
                        f2bf(ac[mi][nj][jj] * wt);
                }
            }
        WAIT_LGKM0;
        bsync();
#pragma unroll
        for (int q = 0; q < 4; q++) {
            int idx = q * 1024 + t;
            int r = idx >> 5, c32 = idx & 31;
            if (r < rv) {
                uint4 v = *(const uint4*)(sH + swz512((unsigned)(r * 512 + c32 * 16)));
                int tok, slice;
                if (routed) { int entry = etk[m0 + r]; tok = entry >> 1; slice = entry & 1; }
                else        { tok = m0 + r; slice = 2; }
                *(uint4*)(slots + ((size_t)slice * TTOK + tok) * HID + n0 + c32 * 8) = v;
            }
        }
        bsync();
    }
}

__global__ __launch_bounds__(256) void k_final(float* __restrict__ out,
                                               const unsigned short* __restrict__ slots) {
    size_t i = ((size_t)blockIdx.x * 256 + threadIdx.x) * 8;
    u16x8 s0 = *(const u16x8*)(slots + i);
    u16x8 s1 = *(const u16x8*)(slots + (size_t)TTOK * HID + i);
    u16x8 s2 = *(const u16x8*)(slots + (size_t)2 * TTOK * HID + i);
    float4 o0, o1;
    o0.x = bf2f(s0[0]) + bf2f(s1[0]) + bf2f(s2[0]);
    o0.y = bf2f(s0[1]) + bf2f(s1[1]) + bf2f(s2[1]);
    o0.z = bf2f(s0[2]) + bf2f(s1[2]) + bf2f(s2[2]);
    o0.w = bf2f(s0[3]) + bf2f(s1[3]) + bf2f(s2[3]);
    o1.x = bf2f(s0[4]) + bf2f(s1[4]) + bf2f(s2[4]);
    o1.y = bf2f(s0[5]) + bf2f(s1[5]) + bf2f(s2[5]);
    o1.z = bf2f(s0[6]) + bf2f(s1[6]) + bf2f(s2[6]);
    o1.w = bf2f(s0[7]) + bf2f(s1[7]) + bf2f(s2[7]);
    *(float4*)(out + i) = o0;
    *(float4*)(out + i + 4) = o1;
}

extern "C" void kernel_launch(void* const* d_in, const int* in_sizes, int n_in,
                              void* d_out, int out_size, void* d_ws, size_t ws_size,
                              hipStream_t stream) {
    const float* x = (const float*)d_in[0];
    const float* gate_w = (const float*)d_in[1];
    const float* cls_w = (const float*)d_in[2];
    const float* escale = (const float*)d_in[3];
    const float* ebias = (const float*)d_in[4];
    const float* wg = (const float*)d_in[5];
    const float* wu = (const float*)d_in[6];
    const float* wd = (const float*)d_in[7];
    const float* sg = (const float*)d_in[8];
    const float* su = (const float*)d_in[9];
    const float* sd = (const float*)d_in[10];
    float* out = (float*)d_out;

    char* ws = (char*)d_ws;
    size_t o = 0;
    auto alloc = [&](size_t bytes) {
        char* p = ws + o;
        o += (bytes + 255) & ~(size_t)255;
        return p;
    };
    const size_t WN = (size_t)NEXP * INTER * HID;
    const size_t SN = (size_t)SINTER * HID;
    unsigned short* xb    = (unsigned short*)alloc((size_t)TTOK * HID * 2);
    unsigned short* hbuf  = (unsigned short*)alloc((size_t)TTOK * SINTER * 2);
    unsigned short* abuf  = (unsigned short*)alloc((size_t)2 * TTOK * INTER * 2);
    unsigned short* slots = (unsigned short*)alloc((size_t)3 * TTOK * HID * 2);
    unsigned short* wgb   = (unsigned short*)alloc(WN * 2);
    unsigned short* wub   = (unsigned short*)alloc(WN * 2);
    unsigned short* wdb   = (unsigned short*)alloc(WN * 2);
    unsigned short* sgb   = (unsigned short*)alloc(SN * 2);
    unsigned short* subb  = (unsigned short*)alloc(SN * 2);
    unsigned short* sdb   = (unsigned short*)alloc(SN * 2);
    int* cnt              = (int*)alloc(256);
    int* offs             = (int*)alloc(256);
    int* etok             = (int*)alloc((size_t)NEXP * TTOK * 4);
    float* ew             = (float*)alloc((size_t)NEXP * TTOK * 4);

    k_zero<<<1, 64, 0, stream>>>(cnt);
    k_w2b<<<4096, 256, 0, stream>>>(wg, wgb, (int)(WN / 8));
    k_w2b<<<4096, 256, 0, stream>>>(wu, wub, (int)(WN / 8));
    k_w2b<<<4096, 256, 0, stream>>>(wd, wdb, (int)(WN / 8));
    k_w2b<<<1024, 256, 0, stream>>>(sg, sgb, (int)(SN / 8));
    k_w2b<<<1024, 256, 0, stream>>>(su, subb, (int)(SN / 8));
    k_w2b<<<1024, 256, 0, stream>>>(sd, sdb, (int)(SN / 8));
    k_router<<<512, 256, 0, stream>>>(x, gate_w, cls_w, escale, ebias, cnt, etok, ew, xb);
    k_offsets<<<1, 64, 0, stream>>>(cnt, offs);
    k_glu10<<<GLU_SH + GLU_RT, 1024, 0, stream>>>(
        xb, wgb, wub, sgb, subb, abuf, hbuf, cnt, offs, etok);
    k_down13<<<DWN_SH + DWN_RT, 1024, 0, stream>>>(
        abuf, hbuf, wdb, sdb, slots, cnt, offs, etok, ew);
    k_final<<<2048, 256, 0, stream>>>(out, slots);
}

// Round 14
// 622.774 us; speedup vs baseline: 2.6655x; 1.0621x over previous
//
#include <hip/hip_runtime.h>

#define HID 2048
#define INTER 1408
#define NEXP 14
#define SINTER 2816
#define TTOK 2048
#define BM 256
#define BK 64

#define GLU_SH 88    // 22 nt x 4 m-slices (shared)
#define GLU_RT 154   // 14 e x 11 nt
#define DWN_SH 64    // 16 nt x 4 ms
#define DWN_RT 224   // 14 e x 16 nt

typedef short bf16x8 __attribute__((ext_vector_type(8)));
typedef float f32x4 __attribute__((ext_vector_type(4)));
typedef unsigned short u16x8 __attribute__((ext_vector_type(8)));

__device__ __forceinline__ unsigned short f2bf(float f) {
    __bf16 b = (__bf16)f;
    return __builtin_bit_cast(unsigned short, b);
}
__device__ __forceinline__ float bf2f(unsigned short u) {
    unsigned v = (unsigned)u << 16;
    return __builtin_bit_cast(float, v);
}
// proven conflict-free swizzles
__device__ __forceinline__ unsigned swz(unsigned b)    { return b ^ (((b >> 7) & 7u) << 4); }
__device__ __forceinline__ unsigned swz256(unsigned b) { return b ^ (((b >> 8) & 7u) << 4); }

__device__ __forceinline__ void gload16(const void* g, void* l) {
    __builtin_amdgcn_global_load_lds((__attribute__((address_space(1))) void*)g,
                                     (__attribute__((address_space(3))) void*)l, 16, 0, 0);
}
__device__ __forceinline__ void bsync() {
    __builtin_amdgcn_sched_barrier(0);
    __builtin_amdgcn_s_barrier();
    __builtin_amdgcn_sched_barrier(0);
}
#define WAIT_VM_(n) asm volatile("s_waitcnt vmcnt(" #n ")" ::: "memory")
#define WAIT_VM(n) WAIT_VM_(n)
#define WAIT_LGKM0 asm volatile("s_waitcnt lgkmcnt(0)" ::: "memory")
#define FENCE __builtin_amdgcn_sched_barrier(0)
#define MFMA16(a, b, c) __builtin_amdgcn_mfma_f32_16x16x32_bf16(a, b, c, 0, 0, 0)

__global__ void k_zero(int* cnt) {
    if ((int)threadIdx.x < NEXP) cnt[threadIdx.x] = 0;
}

// fp32 -> bf16 stream conversion (weights)
__global__ __launch_bounds__(256) void k_w2b(const float* __restrict__ src,
                                             unsigned short* __restrict__ dst, int n8) {
    int stride = gridDim.x * 256;
    for (int i = blockIdx.x * 256 + threadIdx.x; i < n8; i += stride) {
        size_t o = (size_t)i * 8;
        float4 a = *(const float4*)(src + o);
        float4 b = *(const float4*)(src + o + 4);
        u16x8 v;
        v[0] = f2bf(a.x); v[1] = f2bf(a.y); v[2] = f2bf(a.z); v[3] = f2bf(a.w);
        v[4] = f2bf(b.x); v[5] = f2bf(b.y); v[6] = f2bf(b.z); v[7] = f2bf(b.w);
        *(u16x8*)(dst + o) = v;
    }
}

// Router, vectorized + fused x->bf16 store.
__global__ __launch_bounds__(256, 4) void k_router(
    const float* __restrict__ x,
    const float* __restrict__ gate_w, const float* __restrict__ cls_w,
    const float* __restrict__ escale, const float* __restrict__ ebias,
    int* __restrict__ cnt, int* __restrict__ etok, float* __restrict__ ew,
    unsigned short* __restrict__ xb) {
    const int lane = threadIdx.x & 63;
    const int tok = blockIdx.x * 4 + (threadIdx.x >> 6);
    const float* xr = x + (size_t)tok * HID + lane * 4;
    float4 xv[8];
#pragma unroll
    for (int i = 0; i < 8; i++) xv[i] = *(const float4*)(xr + i * 256);
    unsigned short* xbr = xb + (size_t)tok * HID + lane * 4;
#pragma unroll
    for (int i = 0; i < 8; i++) {
        ushort4 v;
        v.x = f2bf(xv[i].x); v.y = f2bf(xv[i].y);
        v.z = f2bf(xv[i].z); v.w = f2bf(xv[i].w);
        *(ushort4*)(xbr + i * 256) = v;
    }

    float sc[NEXP];
    float mx = 0.f;
#pragma unroll
    for (int e = 0; e < NEXP; e++) {
        const float* cw = cls_w + (size_t)e * HID + lane * 4;
        const float* gw = gate_w + (size_t)e * HID + lane * 4;
        float pc = 0.f, pg = 0.f;
        {
            float4 cv[8];
#pragma unroll
            for (int i = 0; i < 8; i++) cv[i] = *(const float4*)(cw + i * 256);
#pragma unroll
            for (int i = 0; i < 8; i++) {
                pc = fmaf(xv[i].x, cv[i].x, pc);
                pc = fmaf(xv[i].y, cv[i].y, pc);
                pc = fmaf(xv[i].z, cv[i].z, pc);
                pc = fmaf(xv[i].w, cv[i].w, pc);
            }
        }
        {
            float4 gv[8];
#pragma unroll
            for (int i = 0; i < 8; i++) gv[i] = *(const float4*)(gw + i * 256);
#pragma unroll
            for (int i = 0; i < 8; i++) {
                pg = fmaf(xv[i].x, gv[i].x, pg);
                pg = fmaf(xv[i].y, gv[i].y, pg);
                pg = fmaf(xv[i].z, gv[i].z, pg);
                pg = fmaf(xv[i].w, gv[i].w, pg);
            }
        }
#pragma unroll
        for (int o = 32; o >= 1; o >>= 1) {
            pc += __shfl_xor(pc, o);
            pg += __shfl_xor(pg, o);
        }
        float lg = pc * (pg / (1.f + __expf(-pg)));
        sc[e] = fabsf(lg);
        mx = fmaxf(mx, sc[e]);
    }
    float s = 0.f;
#pragma unroll
    for (int e = 0; e < NEXP; e++) { sc[e] = __expf(sc[e] - mx); s += sc[e]; }
    float inv = 1.f / s;
    int i1 = -1, i2 = -1;
    float b1 = -1e30f, b2 = -1e30f, v1 = 0.f, v2 = 0.f;
#pragma unroll
    for (int e = 0; e < NEXP; e++) {
        float sv = sc[e] * inv;
        float b = sv + ebias[e];
        if (b > b1) { b2 = b1; i2 = i1; v2 = v1; b1 = b; i1 = e; v1 = sv; }
        else if (b > b2) { b2 = b; i2 = e; v2 = sv; }
    }
    if (lane == 0) {
        float w1 = 1.f + v1 * escale[i1];
        float w2 = 1.f + v2 * escale[i2];
        int p1 = atomicAdd(&cnt[i1], 1);
        etok[i1 * TTOK + p1] = tok * 2;     ew[i1 * TTOK + p1] = w1;
        int p2 = atomicAdd(&cnt[i2], 1);
        etok[i2 * TTOK + p2] = tok * 2 + 1; ew[i2 * TTOK + p2] = w2;
    }
}

__global__ void k_offsets(const int* __restrict__ cnt, int* __restrict__ offs) {
    if (threadIdx.x == 0) {
        int a = 0;
        for (int e = 0; e < NEXP; e++) { offs[e] = a; a += cnt[e]; }
    }
}

// Gate+up GEMM. BM=256, BN=128(G)+128(U), BK=64. A: 2-buf depth-1. B: 3-buf depth-2.
// Exact vmcnt accounting: steady 6, tail 4, last 0.
__global__ __launch_bounds__(1024, 4) void k_glu14(
    const unsigned short* __restrict__ xb,
    const unsigned short* __restrict__ wgb, const unsigned short* __restrict__ wub,
    const unsigned short* __restrict__ sgb, const unsigned short* __restrict__ sub,
    unsigned short* __restrict__ abuf, unsigned short* __restrict__ hbuf,
    const int* __restrict__ cnt, const int* __restrict__ offs,
    const int* __restrict__ etok) {
    __shared__ alignas(16) unsigned short sA[2][BM * BK];    // 64 KB
    __shared__ alignas(16) unsigned short sBg[3][128 * BK];  // 48 KB
    __shared__ alignas(16) unsigned short sBu[3][128 * BK];  // 48 KB  (total 160 KB)

    const int bx = blockIdx.x, t = threadIdx.x;
    const int lane = t & 63, w = t >> 6;
    const int wm = w >> 1, wn = w & 1;
    const int fr = lane & 15, fo = lane >> 4;

    const bool routed = bx >= GLU_SH;
    int n0, m_start, m_stop, obase, Ntot;
    const unsigned short *Bg, *Bu;
    unsigned short* outp;
    const int* etk = nullptr;
    if (routed) {
        int rx = bx - GLU_SH;
        int e = rx / 11; n0 = (rx % 11) * 128;
        int M = cnt[e];
        if (M <= 0) return;
        m_start = 0; m_stop = M; obase = offs[e]; Ntot = INTER;
        Bg = wgb + ((size_t)e * INTER + n0) * HID;
        Bu = wub + ((size_t)e * INTER + n0) * HID;
        outp = abuf; etk = etok + e * TTOK;
    } else {
        n0 = (bx >> 2) * 128;
        m_start = (bx & 3) * 512; m_stop = m_start + 512;
        obase = 0; Ntot = SINTER;
        Bg = sgb + (size_t)n0 * HID;
        Bu = sub + (size_t)n0 * HID;
        outp = hbuf;
    }

    const int browo = lane >> 3;
    const int achunk = (lane & 7) ^ browo;
    const unsigned short* srcBg = Bg + (size_t)(w * 8 + browo) * HID + achunk * 8;
    const unsigned short* srcBu = Bu + (size_t)(w * 8 + browo) * HID + achunk * 8;

    unsigned aoff[2][2], boff[4][2];
#pragma unroll
    for (int mi = 0; mi < 2; mi++)
#pragma unroll
        for (int ks = 0; ks < 2; ks++)
            aoff[mi][ks] = swz((unsigned)((wm * 32 + mi * 16 + fr) * 128 + ks * 64 + fo * 16));
#pragma unroll
    for (int nj = 0; nj < 4; nj++)
#pragma unroll
        for (int ks = 0; ks < 2; ks++)
            boff[nj][ks] = swz((unsigned)((wn * 64 + nj * 16 + fr) * 128 + ks * 64 + fo * 16));

    const int KT = HID / BK;   // 32

    for (int m0 = m_start; m0 < m_stop; m0 += BM) {
        const int rv = min(m_stop - m0, BM);
        const unsigned short* srcA[2];
#pragma unroll
        for (int j = 0; j < 2; j++) {
            int r = w * 16 + j * 8 + browo;
            int rr = r < rv ? r : rv - 1;
            int tok = routed ? (etk[m0 + rr] >> 1) : (m0 + rr);
            srcA[j] = xb + (size_t)tok * HID + achunk * 8;
        }

        f32x4 ag[2][4], au[2][4];
#pragma unroll
        for (int mi = 0; mi < 2; mi++)
#pragma unroll
            for (int nj = 0; nj < 4; nj++) { ag[mi][nj] = {0.f,0.f,0.f,0.f}; au[mi][nj] = {0.f,0.f,0.f,0.f}; }

        // prologue: A(0); B(0); B(1)   [6 loads/wave]
#pragma unroll
        for (int j = 0; j < 2; j++)
            gload16(srcA[j], (char*)sA[0] + w * 2048 + j * 1024);
        gload16(srcBg, (char*)sBg[0] + w * 1024);
        gload16(srcBu, (char*)sBu[0] + w * 1024);
        gload16(srcBg + BK, (char*)sBg[1] + w * 1024);
        gload16(srcBu + BK, (char*)sBu[1] + w * 1024);

        int bcur = 0;
        for (int kk = 0; kk < KT; ++kk) {
            const int acur = kk & 1;
            bsync();   // all waves done reading buffers being overwritten below
            if (kk + 1 < KT) {
                const int k1 = (kk + 1) * BK;
#pragma unroll
                for (int j = 0; j < 2; j++)
                    gload16(srcA[j] + k1, (char*)sA[acur ^ 1] + w * 2048 + j * 1024);
            }
            if (kk + 2 < KT) {
                const int k2 = (kk + 2) * BK;
                int bnx = bcur + 2; if (bnx >= 3) bnx -= 3;
                gload16(srcBg + k2, (char*)sBg[bnx] + w * 1024);
                gload16(srcBu + k2, (char*)sBu[bnx] + w * 1024);
            }
            FENCE;
            if (kk + 2 < KT)      { WAIT_VM(6); }
            else if (kk + 1 < KT) { WAIT_VM(4); }
            else                  { WAIT_VM(0); }
            FENCE;
            bsync();   // stage kk visible to all waves
#pragma unroll
            for (int ks = 0; ks < 2; ++ks) {
                bf16x8 af[2], gf[4], uf[4];
#pragma unroll
                for (int mi = 0; mi < 2; mi++) af[mi] = *(const bf16x8*)((const char*)sA[acur] + aoff[mi][ks]);
#pragma unroll
                for (int nj = 0; nj < 4; nj++) {
                    gf[nj] = *(const bf16x8*)((const char*)sBg[bcur] + boff[nj][ks]);
                    uf[nj] = *(const bf16x8*)((const char*)sBu[bcur] + boff[nj][ks]);
                }
#pragma unroll
                for (int mi = 0; mi < 2; mi++)
#pragma unroll
                    for (int nj = 0; nj < 4; nj++) {
                        ag[mi][nj] = MFMA16(af[mi], gf[nj], ag[mi][nj]);
                        au[mi][nj] = MFMA16(af[mi], uf[nj], au[mi][nj]);
                    }
            }
            bcur = bcur + 1; if (bcur == 3) bcur = 0;
        }

        // epilogue: h = silu(g)*u -> stage bf16 [256][128] over sA -> coalesced sweep
        bsync();
        char* sH = (char*)sA;
#pragma unroll
        for (int mi = 0; mi < 2; mi++)
#pragma unroll
            for (int jj = 0; jj < 4; jj++) {
                int r = wm * 32 + mi * 16 + fo * 4 + jj;
#pragma unroll
                for (int nj = 0; nj < 4; nj++) {
                    int c = wn * 64 + nj * 16 + fr;
                    float g = ag[mi][nj][jj];
                    float u = au[mi][nj][jj];
                    float h = (g / (1.f + __expf(-g))) * u;
                    *(unsigned short*)(sH + swz256((unsigned)(r * 256 + c * 2))) = f2bf(h);
                }
            }
        WAIT_LGKM0;
        bsync();
#pragma unroll
        for (int q = 0; q < 4; q++) {
            int idx = q * 1024 + t;
            int r = idx >> 4, c16 = idx & 15;
            if (r < rv) {
                uint4 v = *(const uint4*)(sH + swz256((unsigned)(r * 256 + c16 * 16)));
                *(uint4*)(outp + (size_t)(obase + m0 + r) * Ntot + n0 + c16 * 8) = v;
            }
        }
        bsync();
    }
}

// Down GEMM. BM=256, BN=128, BK=64. A: 2-buf depth-1. B: 3-buf depth-2.
// vmcnt: steady 4, tail 3, last 0.
__global__ __launch_bounds__(1024, 4) void k_down14(
    const unsigned short* __restrict__ abuf, const unsigned short* __restrict__ hbuf,
    const unsigned short* __restrict__ wdb, const unsigned short* __restrict__ sdb,
    unsigned short* __restrict__ slots,
    const int* __restrict__ cnt, const int* __restrict__ offs,
    const int* __restrict__ etok, const float* __restrict__ ew) {
    __shared__ alignas(16) unsigned short sA[2][BM * BK];   // 64 KB
    __shared__ alignas(16) unsigned short sB[3][128 * BK];  // 48 KB

    const int bx = blockIdx.x, t = threadIdx.x;
    const int lane = t & 63, w = t >> 6;
    const int wm = w >> 1, wn = w & 1;
    const int fr = lane & 15, fo = lane >> 4;

    const bool routed = bx >= DWN_SH;
    int n0, m_start, m_stop, K, KT;
    const unsigned short* W;
    const unsigned short* Abuf;
    size_t arow0 = 0;
    const int* etk = nullptr; const float* ewe = nullptr;
    if (routed) {
        int rx = bx - DWN_SH;
        int e = rx / 16; n0 = (rx % 16) * 128;
        int M = cnt[e];
        if (M <= 0) return;
        m_start = 0; m_stop = M;
        K = INTER; KT = INTER / BK;
        W = wdb + (size_t)e * HID * INTER + (size_t)n0 * INTER;
        Abuf = abuf; arow0 = offs[e];
        etk = etok + e * TTOK; ewe = ew + e * TTOK;
    } else {
        n0 = (bx >> 2) * 128;
        m_start = (bx & 3) * 512; m_stop = m_start + 512;
        K = SINTER; KT = SINTER / BK;
        W = sdb + (size_t)n0 * SINTER;
        Abuf = hbuf;
    }

    const int browo = lane >> 3;
    const int achunk = (lane & 7) ^ browo;
    const unsigned short* srcB = W + (size_t)(w * 8 + browo) * K + achunk * 8;

    unsigned aoff[2][2], boff[4][2];
#pragma unroll
    for (int mi = 0; mi < 2; mi++)
#pragma unroll
        for (int ks = 0; ks < 2; ks++)
            aoff[mi][ks] = swz((unsigned)((wm * 32 + mi * 16 + fr) * 128 + ks * 64 + fo * 16));
#pragma unroll
    for (int nj = 0; nj < 4; nj++)
#pragma unroll
        for (int ks = 0; ks < 2; ks++)
            boff[nj][ks] = swz((unsigned)((wn * 64 + nj * 16 + fr) * 128 + ks * 64 + fo * 16));

    for (int m0 = m_start; m0 < m_stop; m0 += BM) {
        const int rv = min(m_stop - m0, BM);
        const unsigned short* srcA[2];
#pragma unroll
        for (int j = 0; j < 2; j++) {
            int r = w * 16 + j * 8 + browo;
            int rr = r < rv ? r : rv - 1;
            srcA[j] = Abuf + (arow0 + m0 + rr) * (size_t)K + achunk * 8;
        }

        f32x4 ac[2][4];
#pragma unroll
        for (int mi = 0; mi < 2; mi++)
#pragma unroll
            for (int nj = 0; nj < 4; nj++) ac[mi][nj] = {0.f, 0.f, 0.f, 0.f};

        // prologue: A(0); B(0); B(1)
#pragma unroll
        for (int j = 0; j < 2; j++)
            gload16(srcA[j], (char*)sA[0] + w * 2048 + j * 1024);
        gload16(srcB, (char*)sB[0] + w * 1024);
        gload16(srcB + BK, (char*)sB[1] + w * 1024);

        int bcur = 0;
        for (int kk = 0; kk < KT; ++kk) {
            const int acur = kk & 1;
            bsync();
            if (kk + 1 < KT) {
                const int k1 = (kk + 1) * BK;
#pragma unroll
                for (int j = 0; j < 2; j++)
                    gload16(srcA[j] + k1, (char*)sA[acur ^ 1] + w * 2048 + j * 1024);
            }
            if (kk + 2 < KT) {
                const int k2 = (kk + 2) * BK;
                int bnx = bcur + 2; if (bnx >= 3) bnx -= 3;
                gload16(srcB + k2, (char*)sB[bnx] + w * 1024);
            }
            FENCE;
            if (kk + 2 < KT)      { WAIT_VM(4); }
            else if (kk + 1 < KT) { WAIT_VM(3); }
            else                  { WAIT_VM(0); }
            FENCE;
            bsync();
#pragma unroll
            for (int ks = 0; ks < 2; ++ks) {
                bf16x8 af[2], bf[4];
#pragma unroll
                for (int mi = 0; mi < 2; mi++) af[mi] = *(const bf16x8*)((const char*)sA[acur] + aoff[mi][ks]);
#pragma unroll
                for (int nj = 0; nj < 4; nj++) bf[nj] = *(const bf16x8*)((const char*)sB[bcur] + boff[nj][ks]);
#pragma unroll
                for (int mi = 0; mi < 2; mi++)
#pragma unroll
                    for (int nj = 0; nj < 4; nj++)
                        ac[mi][nj] = MFMA16(af[mi], bf[nj], ac[mi][nj]);
            }
            bcur = bcur + 1; if (bcur == 3) bcur = 0;
        }

        // epilogue: scale, stage bf16 [256][128] over sA, sweep to slot slices
        bsync();
        char* sH = (char*)sA;
#pragma unroll
        for (int mi = 0; mi < 2; mi++)
#pragma unroll
            for (int jj = 0; jj < 4; jj++) {
                int r = wm * 32 + mi * 16 + fo * 4 + jj;
                float wt = 1.f;
                if (routed) wt = (r < rv) ? ewe[m0 + r] : 0.f;
#pragma unroll
                for (int nj = 0; nj < 4; nj++) {
                    int c = wn * 64 + nj * 16 + fr;
                    *(unsigned short*)(sH + swz256((unsigned)(r * 256 + c * 2))) =
                        f2bf(ac[mi][nj][jj] * wt);
                }
            }
        WAIT_LGKM0;
        bsync();
#pragma unroll
        for (int q = 0; q < 4; q++) {
            int idx = q * 1024 + t;
            int r = idx >> 4, c16 = idx & 15;
            if (r < rv) {
                uint4 v = *(const uint4*)(sH + swz256((unsigned)(r * 256 + c16 * 16)));
                int tok, slice;
                if (routed) { int entry = etk[m0 + r]; tok = entry >> 1; slice = entry & 1; }
                else        { tok = m0 + r; slice = 2; }
                *(uint4*)(slots + ((size_t)slice * TTOK + tok) * HID + n0 + c16 * 8) = v;
            }
        }
        bsync();
    }
}

__global__ __launch_bounds__(256) void k_final(float* __restrict__ out,
                                               const unsigned short* __restrict__ slots) {
    size_t i = ((size_t)blockIdx.x * 256 + threadIdx.x) * 8;
    u16x8 s0 = *(const u16x8*)(slots + i);
    u16x8 s1 = *(const u16x8*)(slots + (size_t)TTOK * HID + i);
    u16x8 s2 = *(const u16x8*)(slots + (size_t)2 * TTOK * HID + i);
    float4 o0, o1;
    o0.x = bf2f(s0[0]) + bf2f(s1[0]) + bf2f(s2[0]);
    o0.y = bf2f(s0[1]) + bf2f(s1[1]) + bf2f(s2[1]);
    o0.z = bf2f(s0[2]) + bf2f(s1[2]) + bf2f(s2[2]);
    o0.w = bf2f(s0[3]) + bf2f(s1[3]) + bf2f(s2[3]);
    o1.x = bf2f(s0[4]) + bf2f(s1[4]) + bf2f(s2[4]);
    o1.y = bf2f(s0[5]) + bf2f(s1[5]) + bf2f(s2[5]);
    o1.z = bf2f(s0[6]) + bf2f(s1[6]) + bf2f(s2[6]);
    o1.w = bf2f(s0[7]) + bf2f(s1[7]) + bf2f(s2[7]);
    *(float4*)(out + i) = o0;
    *(float4*)(out + i + 4) = o1;
}

extern "C" void kernel_launch(void* const* d_in, const int* in_sizes, int n_in,
                              void* d_out, int out_size, void* d_ws, size_t ws_size,
                              hipStream_t stream) {
    const float* x = (const float*)d_in[0];
    const float* gate_w = (const float*)d_in[1];
    const float* cls_w = (const float*)d_in[2];
    const float* escale = (const float*)d_in[3];
    const float* ebias = (const float*)d_in[4];
    const float* wg = (const float*)d_in[5];
    const float* wu = (const float*)d_in[6];
    const float* wd = (const float*)d_in[7];
    const float* sg = (const float*)d_in[8];
    const float* su = (const float*)d_in[9];
    const float* sd = (const float*)d_in[10];
    float* out = (float*)d_out;

    char* ws = (char*)d_ws;
    size_t o = 0;
    auto alloc = [&](size_t bytes) {
        char* p = ws + o;
        o += (bytes + 255) & ~(size_t)255;
        return p;
    };
    const size_t WN = (size_t)NEXP * INTER * HID;
    const size_t SN = (size_t)SINTER * HID;
    unsigned short* xb    = (unsigned short*)alloc((size_t)TTOK * HID * 2);
    unsigned short* hbuf  = (unsigned short*)alloc((size_t)TTOK * SINTER * 2);
    unsigned short* abuf  = (unsigned short*)alloc((size_t)2 * TTOK * INTER * 2);
    unsigned short* slots = (unsigned short*)alloc((size_t)3 * TTOK * HID * 2);
    unsigned short* wgb   = (unsigned short*)alloc(WN * 2);
    unsigned short* wub   = (unsigned short*)alloc(WN * 2);
    unsigned short* wdb   = (unsigned short*)alloc(WN * 2);
    unsigned short* sgb   = (unsigned short*)alloc(SN * 2);
    unsigned short* subb  = (unsigned short*)alloc(SN * 2);
    unsigned short* sdb   = (unsigned short*)alloc(SN * 2);
    int* cnt              = (int*)alloc(256);
    int* offs             = (int*)alloc(256);
    int* etok             = (int*)alloc((size_t)NEXP * TTOK * 4);
    float* ew             = (float*)alloc((size_t)NEXP * TTOK * 4);

    k_zero<<<1, 64, 0, stream>>>(cnt);
    k_w2b<<<4096, 256, 0, stream>>>(wg, wgb, (int)(WN / 8));
    k_w2b<<<4096, 256, 0, stream>>>(wu, wub, (int)(WN / 8));
    k_w2b<<<4096, 256, 0, stream>>>(wd, wdb, (int)(WN / 8));
    k_w2b<<<1024, 256, 0, stream>>>(sg, sgb, (int)(SN / 8));
    k_w2b<<<1024, 256, 0, stream>>>(su, subb, (int)(SN / 8));
    k_w2b<<<1024, 256, 0, stream>>>(sd, sdb, (int)(SN / 8));
    k_router<<<512, 256, 0, stream>>>(x, gate_w, cls_w, escale, ebias, cnt, etok, ew, xb);
    k_offsets<<<1, 64, 0, stream>>>(cnt, offs);
    k_glu14<<<GLU_SH + GLU_RT, 1024, 0, stream>>>(
        xb, wgb, wub, sgb, subb, abuf, hbuf, cnt, offs, etok);
    k_down14<<<DWN_SH + DWN_RT, 1024, 0, stream>>>(
        abuf, hbuf, wdb, sdb, slots, cnt, offs, etok, ew);
    k_final<<<2048, 256, 0, stream>>>(out, slots);
}

// Round 15
// 620.600 us; speedup vs baseline: 2.6749x; 1.0035x over previous
//
#include <hip/hip_runtime.h>

#define HID 2048
#define INTER 1408
#define NEXP 14
#define SINTER 2816
#define TTOK 2048
#define BM 256
#define BK 64

#define GLU_SH 88    // 22 nt x 4 m-slices (shared)
#define GLU_RT 154   // 14 e x 11 nt
#define DWN_SH 64    // 16 nt x 4 ms
#define DWN_RT 224   // 14 e x 16 nt

typedef short bf16x8 __attribute__((ext_vector_type(8)));
typedef float f32x4 __attribute__((ext_vector_type(4)));
typedef unsigned short u16x8 __attribute__((ext_vector_type(8)));

__device__ __forceinline__ unsigned short f2bf(float f) {
    __bf16 b = (__bf16)f;
    return __builtin_bit_cast(unsigned short, b);
}
__device__ __forceinline__ float bf2f(unsigned short u) {
    unsigned v = (unsigned)u << 16;
    return __builtin_bit_cast(float, v);
}
// proven conflict-free swizzles
__device__ __forceinline__ unsigned swz(unsigned b)    { return b ^ (((b >> 7) & 7u) << 4); }
__device__ __forceinline__ unsigned swz256(unsigned b) { return b ^ (((b >> 8) & 7u) << 4); }

__device__ __forceinline__ void gload16(const void* g, void* l) {
    __builtin_amdgcn_global_load_lds((__attribute__((address_space(1))) void*)g,
                                     (__attribute__((address_space(3))) void*)l, 16, 0, 0);
}
__device__ __forceinline__ void bsync() {
    __builtin_amdgcn_sched_barrier(0);
    __builtin_amdgcn_s_barrier();
    __builtin_amdgcn_sched_barrier(0);
}
#define WAIT_VM_(n) asm volatile("s_waitcnt vmcnt(" #n ")" ::: "memory")
#define WAIT_VM(n) WAIT_VM_(n)
#define WAIT_LGKM0 asm volatile("s_waitcnt lgkmcnt(0)" ::: "memory")
#define FENCE __builtin_amdgcn_sched_barrier(0)
#define MFMA16(a, b, c) __builtin_amdgcn_mfma_f32_16x16x32_bf16(a, b, c, 0, 0, 0)

__global__ void k_zero(int* cnt) {
    if ((int)threadIdx.x < NEXP) cnt[threadIdx.x] = 0;
}

// fp32 -> bf16 stream conversion (weights)
__global__ __launch_bounds__(256) void k_w2b(const float* __restrict__ src,
                                             unsigned short* __restrict__ dst, int n8) {
    int stride = gridDim.x * 256;
    for (int i = blockIdx.x * 256 + threadIdx.x; i < n8; i += stride) {
        size_t o = (size_t)i * 8;
        float4 a = *(const float4*)(src + o);
        float4 b = *(const float4*)(src + o + 4);
        u16x8 v;
        v[0] = f2bf(a.x); v[1] = f2bf(a.y); v[2] = f2bf(a.z); v[3] = f2bf(a.w);
        v[4] = f2bf(b.x); v[5] = f2bf(b.y); v[6] = f2bf(b.z); v[7] = f2bf(b.w);
        *(u16x8*)(dst + o) = v;
    }
}

// Router, vectorized + fused x->bf16 store.
__global__ __launch_bounds__(256, 4) void k_router(
    const float* __restrict__ x,
    const float* __restrict__ gate_w, const float* __restrict__ cls_w,
    const float* __restrict__ escale, const float* __restrict__ ebias,
    int* __restrict__ cnt, int* __restrict__ etok, float* __restrict__ ew,
    unsigned short* __restrict__ xb) {
    const int lane = threadIdx.x & 63;
    const int tok = blockIdx.x * 4 + (threadIdx.x >> 6);
    const float* xr = x + (size_t)tok * HID + lane * 4;
    float4 xv[8];
#pragma unroll
    for (int i = 0; i < 8; i++) xv[i] = *(const float4*)(xr + i * 256);
    unsigned short* xbr = xb + (size_t)tok * HID + lane * 4;
#pragma unroll
    for (int i = 0; i < 8; i++) {
        ushort4 v;
        v.x = f2bf(xv[i].x); v.y = f2bf(xv[i].y);
        v.z = f2bf(xv[i].z); v.w = f2bf(xv[i].w);
        *(ushort4*)(xbr + i * 256) = v;
    }

    float sc[NEXP];
    float mx = 0.f;
#pragma unroll
    for (int e = 0; e < NEXP; e++) {
        const float* cw = cls_w + (size_t)e * HID + lane * 4;
        const float* gw = gate_w + (size_t)e * HID + lane * 4;
        float pc = 0.f, pg = 0.f;
        {
            float4 cv[8];
#pragma unroll
            for (int i = 0; i < 8; i++) cv[i] = *(const float4*)(cw + i * 256);
#pragma unroll
            for (int i = 0; i < 8; i++) {
                pc = fmaf(xv[i].x, cv[i].x, pc);
                pc = fmaf(xv[i].y, cv[i].y, pc);
                pc = fmaf(xv[i].z, cv[i].z, pc);
                pc = fmaf(xv[i].w, cv[i].w, pc);
            }
        }
        {
            float4 gv[8];
#pragma unroll
            for (int i = 0; i < 8; i++) gv[i] = *(const float4*)(gw + i * 256);
#pragma unroll
            for (int i = 0; i < 8; i++) {
                pg = fmaf(xv[i].x, gv[i].x, pg);
                pg = fmaf(xv[i].y, gv[i].y, pg);
                pg = fmaf(xv[i].z, gv[i].z, pg);
                pg = fmaf(xv[i].w, gv[i].w, pg);
            }
        }
#pragma unroll
        for (int o = 32; o >= 1; o >>= 1) {
            pc += __shfl_xor(pc, o);
            pg += __shfl_xor(pg, o);
        }
        float lg = pc * (pg / (1.f + __expf(-pg)));
        sc[e] = fabsf(lg);
        mx = fmaxf(mx, sc[e]);
    }
    float s = 0.f;
#pragma unroll
    for (int e = 0; e < NEXP; e++) { sc[e] = __expf(sc[e] - mx); s += sc[e]; }
    float inv = 1.f / s;
    int i1 = -1, i2 = -1;
    float b1 = -1e30f, b2 = -1e30f, v1 = 0.f, v2 = 0.f;
#pragma unroll
    for (int e = 0; e < NEXP; e++) {
        float sv = sc[e] * inv;
        float b = sv + ebias[e];
        if (b > b1) { b2 = b1; i2 = i1; v2 = v1; b1 = b; i1 = e; v1 = sv; }
        else if (b > b2) { b2 = b; i2 = e; v2 = sv; }
    }
    if (lane == 0) {
        float w1 = 1.f + v1 * escale[i1];
        float w2 = 1.f + v2 * escale[i2];
        int p1 = atomicAdd(&cnt[i1], 1);
        etok[i1 * TTOK + p1] = tok * 2;     ew[i1 * TTOK + p1] = w1;
        int p2 = atomicAdd(&cnt[i2], 1);
        etok[i2 * TTOK + p2] = tok * 2 + 1; ew[i2 * TTOK + p2] = w2;
    }
}

__global__ void k_offsets(const int* __restrict__ cnt, int* __restrict__ offs) {
    if (threadIdx.x == 0) {
        int a = 0;
        for (int e = 0; e < NEXP; e++) { offs[e] = a; a += cnt[e]; }
    }
}

// Gate+up GEMM. BM=256, BN=128(G)+128(U), BK=64. A: 2-buf. B: 3-buf ring.
// SINGLE barrier per k-iter: wait(counted) -> bsync -> issue A(k+1),B(k+2) -> MFMA(k).
__global__ __launch_bounds__(1024, 4) void k_glu15(
    const unsigned short* __restrict__ xb,
    const unsigned short* __restrict__ wgb, const unsigned short* __restrict__ wub,
    const unsigned short* __restrict__ sgb, const unsigned short* __restrict__ sub,
    unsigned short* __restrict__ abuf, unsigned short* __restrict__ hbuf,
    const int* __restrict__ cnt, const int* __restrict__ offs,
    const int* __restrict__ etok) {
    __shared__ alignas(16) unsigned short sA[2][BM * BK];    // 64 KB
    __shared__ alignas(16) unsigned short sBg[3][128 * BK];  // 48 KB
    __shared__ alignas(16) unsigned short sBu[3][128 * BK];  // 48 KB

    const int bx = blockIdx.x, t = threadIdx.x;
    const int lane = t & 63, w = t >> 6;
    const int wm = w >> 1, wn = w & 1;
    const int fr = lane & 15, fo = lane >> 4;

    const bool routed = bx >= GLU_SH;
    int n0, m_start, m_stop, obase, Ntot;
    const unsigned short *Bg, *Bu;
    unsigned short* outp;
    const int* etk = nullptr;
    if (routed) {
        int rx = bx - GLU_SH;
        int e = rx / 11; n0 = (rx % 11) * 128;
        int M = cnt[e];
        if (M <= 0) return;
        m_start = 0; m_stop = M; obase = offs[e]; Ntot = INTER;
        Bg = wgb + ((size_t)e * INTER + n0) * HID;
        Bu = wub + ((size_t)e * INTER + n0) * HID;
        outp = abuf; etk = etok + e * TTOK;
    } else {
        n0 = (bx >> 2) * 128;
        m_start = (bx & 3) * 512; m_stop = m_start + 512;
        obase = 0; Ntot = SINTER;
        Bg = sgb + (size_t)n0 * HID;
        Bu = sub + (size_t)n0 * HID;
        outp = hbuf;
    }

    const int browo = lane >> 3;
    const int achunk = (lane & 7) ^ browo;
    const unsigned short* srcBg = Bg + (size_t)(w * 8 + browo) * HID + achunk * 8;
    const unsigned short* srcBu = Bu + (size_t)(w * 8 + browo) * HID + achunk * 8;

    unsigned aoff[2][2], boff[4][2];
#pragma unroll
    for (int mi = 0; mi < 2; mi++)
#pragma unroll
        for (int ks = 0; ks < 2; ks++)
            aoff[mi][ks] = swz((unsigned)((wm * 32 + mi * 16 + fr) * 128 + ks * 64 + fo * 16));
#pragma unroll
    for (int nj = 0; nj < 4; nj++)
#pragma unroll
        for (int ks = 0; ks < 2; ks++)
            boff[nj][ks] = swz((unsigned)((wn * 64 + nj * 16 + fr) * 128 + ks * 64 + fo * 16));

    const int KT = HID / BK;   // 32

    for (int m0 = m_start; m0 < m_stop; m0 += BM) {
        const int rv = min(m_stop - m0, BM);
        const unsigned short* srcA[2];
#pragma unroll
        for (int j = 0; j < 2; j++) {
            int r = w * 16 + j * 8 + browo;
            int rr = r < rv ? r : rv - 1;
            int tok = routed ? (etk[m0 + rr] >> 1) : (m0 + rr);
            srcA[j] = xb + (size_t)tok * HID + achunk * 8;
        }

        f32x4 ag[2][4], au[2][4];
#pragma unroll
        for (int mi = 0; mi < 2; mi++)
#pragma unroll
            for (int nj = 0; nj < 4; nj++) { ag[mi][nj] = {0.f,0.f,0.f,0.f}; au[mi][nj] = {0.f,0.f,0.f,0.f}; }

        // prologue: A(0)->sA[0]; B(0)->sB[0]; B(1)->sB[1]
#pragma unroll
        for (int j = 0; j < 2; j++)
            gload16(srcA[j], (char*)sA[0] + w * 2048 + j * 1024);
        gload16(srcBg, (char*)sBg[0] + w * 1024);
        gload16(srcBu, (char*)sBu[0] + w * 1024);
        gload16(srcBg + BK, (char*)sBg[1] + w * 1024);
        gload16(srcBu + BK, (char*)sBu[1] + w * 1024);

        int bcur = 0;
        for (int kk = 0; kk < KT; ++kk) {
            const int acur = kk & 1;
            // tile kk drained; B(kk+1)'s 2 loads may stay in flight
            FENCE;
            if (kk + 1 < KT) { WAIT_VM(2); } else { WAIT_VM(0); }
            FENCE;
            bsync();   // all waves: tile kk ready, tile kk-1 reads done
            // issue next tiles (overwrite buffers holding tile kk-1: safe post-barrier)
            if (kk + 1 < KT) {
                const int k1 = (kk + 1) * BK;
#pragma unroll
                for (int j = 0; j < 2; j++)
                    gload16(srcA[j] + k1, (char*)sA[acur ^ 1] + w * 2048 + j * 1024);
            }
            if (kk + 2 < KT) {
                const int k2 = (kk + 2) * BK;
                int bnx = bcur + 2; if (bnx >= 3) bnx -= 3;
                gload16(srcBg + k2, (char*)sBg[bnx] + w * 1024);
                gload16(srcBu + k2, (char*)sBu[bnx] + w * 1024);
            }
            FENCE;
#pragma unroll
            for (int ks = 0; ks < 2; ++ks) {
                bf16x8 af[2], gf[4], uf[4];
#pragma unroll
                for (int mi = 0; mi < 2; mi++) af[mi] = *(const bf16x8*)((const char*)sA[acur] + aoff[mi][ks]);
#pragma unroll
                for (int nj = 0; nj < 4; nj++) {
                    gf[nj] = *(const bf16x8*)((const char*)sBg[bcur] + boff[nj][ks]);
                    uf[nj] = *(const bf16x8*)((const char*)sBu[bcur] + boff[nj][ks]);
                }
#pragma unroll
                for (int mi = 0; mi < 2; mi++)
#pragma unroll
                    for (int nj = 0; nj < 4; nj++) {
                        ag[mi][nj] = MFMA16(af[mi], gf[nj], ag[mi][nj]);
                        au[mi][nj] = MFMA16(af[mi], uf[nj], au[mi][nj]);
                    }
            }
            bcur = bcur + 1; if (bcur == 3) bcur = 0;
        }

        // epilogue: h = silu(g)*u -> stage bf16 [256][128] over sA -> coalesced sweep
        bsync();   // all waves done with final MFMA reads before overwriting sA
        char* sH = (char*)sA;
#pragma unroll
        for (int mi = 0; mi < 2; mi++)
#pragma unroll
            for (int jj = 0; jj < 4; jj++) {
                int r = wm * 32 + mi * 16 + fo * 4 + jj;
#pragma unroll
                for (int nj = 0; nj < 4; nj++) {
                    int c = wn * 64 + nj * 16 + fr;
                    float g = ag[mi][nj][jj];
                    float u = au[mi][nj][jj];
                    float h = (g / (1.f + __expf(-g))) * u;
                    *(unsigned short*)(sH + swz256((unsigned)(r * 256 + c * 2))) = f2bf(h);
                }
            }
        WAIT_LGKM0;
        bsync();
#pragma unroll
        for (int q = 0; q < 4; q++) {
            int idx = q * 1024 + t;
            int r = idx >> 4, c16 = idx & 15;
            if (r < rv) {
                uint4 v = *(const uint4*)(sH + swz256((unsigned)(r * 256 + c16 * 16)));
                *(uint4*)(outp + (size_t)(obase + m0 + r) * Ntot + n0 + c16 * 8) = v;
            }
        }
        bsync();
    }
}

// Down GEMM. BM=256, BN=128, BK=64. A: 2-buf. B: 3-buf ring. Single barrier/iter.
__global__ __launch_bounds__(1024, 4) void k_down15(
    const unsigned short* __restrict__ abuf, const unsigned short* __restrict__ hbuf,
    const unsigned short* __restrict__ wdb, const unsigned short* __restrict__ sdb,
    unsigned short* __restrict__ slots,
    const int* __restrict__ cnt, const int* __restrict__ offs,
    const int* __restrict__ etok, const float* __restrict__ ew) {
    __shared__ alignas(16) unsigned short sA[2][BM * BK];   // 64 KB
    __shared__ alignas(16) unsigned short sB[3][128 * BK];  // 48 KB

    const int bx = blockIdx.x, t = threadIdx.x;
    const int lane = t & 63, w = t >> 6;
    const int wm = w >> 1, wn = w & 1;
    const int fr = lane & 15, fo = lane >> 4;

    const bool routed = bx >= DWN_SH;
    int n0, m_start, m_stop, K, KT;
    const unsigned short* W;
    const unsigned short* Abuf;
    size_t arow0 = 0;
    const int* etk = nullptr; const float* ewe = nullptr;
    if (routed) {
        int rx = bx - DWN_SH;
        int e = rx / 16; n0 = (rx % 16) * 128;
        int M = cnt[e];
        if (M <= 0) return;
        m_start = 0; m_stop = M;
        K = INTER; KT = INTER / BK;
        W = wdb + (size_t)e * HID * INTER + (size_t)n0 * INTER;
        Abuf = abuf; arow0 = offs[e];
        etk = etok + e * TTOK; ewe = ew + e * TTOK;
    } else {
        n0 = (bx >> 2) * 128;
        m_start = (bx & 3) * 512; m_stop = m_start + 512;
        K = SINTER; KT = SINTER / BK;
        W = sdb + (size_t)n0 * SINTER;
        Abuf = hbuf;
    }

    const int browo = lane >> 3;
    const int achunk = (lane & 7) ^ browo;
    const unsigned short* srcB = W + (size_t)(w * 8 + browo) * K + achunk * 8;

    unsigned aoff[2][2], boff[4][2];
#pragma unroll
    for (int mi = 0; mi < 2; mi++)
#pragma unroll
        for (int ks = 0; ks < 2; ks++)
            aoff[mi][ks] = swz((unsigned)((wm * 32 + mi * 16 + fr) * 128 + ks * 64 + fo * 16));
#pragma unroll
    for (int nj = 0; nj < 4; nj++)
#pragma unroll
        for (int ks = 0; ks < 2; ks++)
            boff[nj][ks] = swz((unsigned)((wn * 64 + nj * 16 + fr) * 128 + ks * 64 + fo * 16));

    for (int m0 = m_start; m0 < m_stop; m0 += BM) {
        const int rv = min(m_stop - m0, BM);
        const unsigned short* srcA[2];
#pragma unroll
        for (int j = 0; j < 2; j++) {
            int r = w * 16 + j * 8 + browo;
            int rr = r < rv ? r : rv - 1;
            srcA[j] = Abuf + (arow0 + m0 + rr) * (size_t)K + achunk * 8;
        }

        f32x4 ac[2][4];
#pragma unroll
        for (int mi = 0; mi < 2; mi++)
#pragma unroll
            for (int nj = 0; nj < 4; nj++) ac[mi][nj] = {0.f, 0.f, 0.f, 0.f};

        // prologue: A(0); B(0); B(1)
#pragma unroll
        for (int j = 0; j < 2; j++)
            gload16(srcA[j], (char*)sA[0] + w * 2048 + j * 1024);
        gload16(srcB, (char*)sB[0] + w * 1024);
        gload16(srcB + BK, (char*)sB[1] + w * 1024);

        int bcur = 0;
        for (int kk = 0; kk < KT; ++kk) {
            const int acur = kk & 1;
            FENCE;
            if (kk + 1 < KT) { WAIT_VM(1); } else { WAIT_VM(0); }
            FENCE;
            bsync();
            if (kk + 1 < KT) {
                const int k1 = (kk + 1) * BK;
#pragma unroll
                for (int j = 0; j < 2; j++)
                    gload16(srcA[j] + k1, (char*)sA[acur ^ 1] + w * 2048 + j * 1024);
            }
            if (kk + 2 < KT) {
                const int k2 = (kk + 2) * BK;
                int bnx = bcur + 2; if (bnx >= 3) bnx -= 3;
                gload16(srcB + k2, (char*)sB[bnx] + w * 1024);
            }
            FENCE;
#pragma unroll
            for (int ks = 0; ks < 2; ++ks) {
                bf16x8 af[2], bf[4];
#pragma unroll
                for (int mi = 0; mi < 2; mi++) af[mi] = *(const bf16x8*)((const char*)sA[acur] + aoff[mi][ks]);
#pragma unroll
                for (int nj = 0; nj < 4; nj++) bf[nj] = *(const bf16x8*)((const char*)sB[bcur] + boff[nj][ks]);
#pragma unroll
                for (int mi = 0; mi < 2; mi++)
#pragma unroll
                    for (int nj = 0; nj < 4; nj++)
                        ac[mi][nj] = MFMA16(af[mi], bf[nj], ac[mi][nj]);
            }
            bcur = bcur + 1; if (bcur == 3) bcur = 0;
        }

        // epilogue: scale, stage bf16 [256][128] over sA, sweep to slot slices
        bsync();
        char* sH = (char*)sA;
#pragma unroll
        for (int mi = 0; mi < 2; mi++)
#pragma unroll
            for (int jj = 0; jj < 4; jj++) {
                int r = wm * 32 + mi * 16 + fo * 4 + jj;
                float wt = 1.f;
                if (routed) wt = (r < rv) ? ewe[m0 + r] : 0.f;
#pragma unroll
                for (int nj = 0; nj < 4; nj++) {
                    int c = wn * 64 + nj * 16 + fr;
                    *(unsigned short*)(sH + swz256((unsigned)(r * 256 + c * 2))) =
                        f2bf(ac[mi][nj][jj] * wt);
                }
            }
        WAIT_LGKM0;
        bsync();
#pragma unroll
        for (int q = 0; q < 4; q++) {
            int idx = q * 1024 + t;
            int r = idx >> 4, c16 = idx & 15;
            if (r < rv) {
                uint4 v = *(const uint4*)(sH + swz256((unsigned)(r * 256 + c16 * 16)));
                int tok, slice;
                if (routed) { int entry = etk[m0 + r]; tok = entry >> 1; slice = entry & 1; }
                else        { tok = m0 + r; slice = 2; }
                *(uint4*)(slots + ((size_t)slice * TTOK + tok) * HID + n0 + c16 * 8) = v;
            }
        }
        bsync();
    }
}

__global__ __launch_bounds__(256) void k_final(float* __restrict__ out,
                                               const unsigned short* __restrict__ slots) {
    size_t i = ((size_t)blockIdx.x * 256 + threadIdx.x) * 8;
    u16x8 s0 = *(const u16x8*)(slots + i);
    u16x8 s1 = *(const u16x8*)(slots + (size_t)TTOK * HID + i);
    u16x8 s2 = *(const u16x8*)(slots + (size_t)2 * TTOK * HID + i);
    float4 o0, o1;
    o0.x = bf2f(s0[0]) + bf2f(s1[0]) + bf2f(s2[0]);
    o0.y = bf2f(s0[1]) + bf2f(s1[1]) + bf2f(s2[1]);
    o0.z = bf2f(s0[2]) + bf2f(s1[2]) + bf2f(s2[2]);
    o0.w = bf2f(s0[3]) + bf2f(s1[3]) + bf2f(s2[3]);
    o1.x = bf2f(s0[4]) + bf2f(s1[4]) + bf2f(s2[4]);
    o1.y = bf2f(s0[5]) + bf2f(s1[5]) + bf2f(s2[5]);
    o1.z = bf2f(s0[6]) + bf2f(s1[6]) + bf2f(s2[6]);
    o1.w = bf2f(s0[7]) + bf2f(s1[7]) + bf2f(s2[7]);
    *(float4*)(out + i) = o0;
    *(float4*)(out + i + 4) = o1;
}

extern "C" void kernel_launch(void* const* d_in, const int* in_sizes, int n_in,
                              void* d_out, int out_size, void* d_ws, size_t ws_size,
                              hipStream_t stream) {
    const float* x = (const float*)d_in[0];
    const float* gate_w = (const float*)d_in[1];
    const float* cls_w = (const float*)d_in[2];
    const float* escale = (const float*)d_in[3];
    const float* ebias = (const float*)d_in[4];
    const float* wg = (const float*)d_in[5];
    const float* wu = (const float*)d_in[6];
    const float* wd = (const float*)d_in[7];
    const float* sg = (const float*)d_in[8];
    const float* su = (const float*)d_in[9];
    const float* sd = (const float*)d_in[10];
    float* out = (float*)d_out;

    char* ws = (char*)d_ws;
    size_t o = 0;
    auto alloc = [&](size_t bytes) {
        char* p = ws + o;
        o += (bytes + 255) & ~(size_t)255;
        return p;
    };
    const size_t WN = (size_t)NEXP * INTER * HID;
    const size_t SN = (size_t)SINTER * HID;
    unsigned short* xb    = (unsigned short*)alloc((size_t)TTOK * HID * 2);
    unsigned short* hbuf  = (unsigned short*)alloc((size_t)TTOK * SINTER * 2);
    unsigned short* abuf  = (unsigned short*)alloc((size_t)2 * TTOK * INTER * 2);
    unsigned short* slots = (unsigned short*)alloc((size_t)3 * TTOK * HID * 2);
    unsigned short* wgb   = (unsigned short*)alloc(WN * 2);
    unsigned short* wub   = (unsigned short*)alloc(WN * 2);
    unsigned short* wdb   = (unsigned short*)alloc(WN * 2);
    unsigned short* sgb   = (unsigned short*)alloc(SN * 2);
    unsigned short* subb  = (unsigned short*)alloc(SN * 2);
    unsigned short* sdb   = (unsigned short*)alloc(SN * 2);
    int* cnt              = (int*)alloc(256);
    int* offs             = (int*)alloc(256);
    int* etok             = (int*)alloc((size_t)NEXP * TTOK * 4);
    float* ew             = (float*)alloc((size_t)NEXP * TTOK * 4);

    k_zero<<<1, 64, 0, stream>>>(cnt);
    k_w2b<<<4096, 256, 0, stream>>>(wg, wgb, (int)(WN / 8));
    k_w2b<<<4096, 256, 0, stream>>>(wu, wub, (int)(WN / 8));
    k_w2b<<<4096, 256, 0, stream>>>(wd, wdb, (int)(WN / 8));
    k_w2b<<<1024, 256, 0, stream>>>(sg, sgb, (int)(SN / 8));
    k_w2b<<<1024, 256, 0, stream>>>(su, subb, (int)(SN / 8));
    k_w2b<<<1024, 256, 0, stream>>>(sd, sdb, (int)(SN / 8));
    k_router<<<512, 256, 0, stream>>>(x, gate_w, cls_w, escale, ebias, cnt, etok, ew, xb);
    k_offsets<<<1, 64, 0, stream>>>(cnt, offs);
    k_glu15<<<GLU_SH + GLU_RT, 1024, 0, stream>>>(
        xb, wgb, wub, sgb, subb, abuf, hbuf, cnt, offs, etok);
    k_down15<<<DWN_SH + DWN_RT, 1024, 0, stream>>>(
        abuf, hbuf, wdb, sdb, slots, cnt, offs, etok, ew);
    k_final<<<2048, 256, 0, stream>>>(out, slots);
}

// Round 16
// 537.404 us; speedup vs baseline: 3.0890x; 1.1548x over previous
//
#include <hip/hip_runtime.h>

#define HID 2048
#define INTER 1408
#define NEXP 14
#define SINTER 2816
#define TTOK 2048
#define BM 384
#define BK 64

#define GLU_SH 264   // 44 nt x 6 m-slices (shared first)
#define GLU_RT 308   // 14 e x 22 nt
#define DWN_SH 96    // 16 nt x 6 m-slices
#define DWN_RT 224   // 14 e x 16 nt

typedef short bf16x8 __attribute__((ext_vector_type(8)));
typedef float f32x4 __attribute__((ext_vector_type(4)));
typedef unsigned short u16x8 __attribute__((ext_vector_type(8)));

__device__ __forceinline__ unsigned short f2bf(float f) {
    __bf16 b = (__bf16)f;
    return __builtin_bit_cast(unsigned short, b);
}
__device__ __forceinline__ float bf2f(unsigned short u) {
    unsigned v = (unsigned)u << 16;
    return __builtin_bit_cast(float, v);
}
// XOR swizzle for 128B-stride rows (conflict-free, proven R4/R6/R9)
__device__ __forceinline__ unsigned swz(unsigned b) { return b ^ (((b >> 7) & 7u) << 4); }

__device__ __forceinline__ void gload16(const void* g, void* l) {
    __builtin_amdgcn_global_load_lds((__attribute__((address_space(1))) void*)g,
                                     (__attribute__((address_space(3))) void*)l, 16, 0, 0);
}
__device__ __forceinline__ void bsync() {
    __builtin_amdgcn_sched_barrier(0);
    __builtin_amdgcn_s_barrier();
    __builtin_amdgcn_sched_barrier(0);
}
#define WAIT_LGKM0 asm volatile("s_waitcnt lgkmcnt(0)" ::: "memory")

__global__ void k_zero(int* cnt) {
    if ((int)threadIdx.x < NEXP) cnt[threadIdx.x] = 0;
}

// Router, vectorized (R11-proven) + fused x->bf16 store.
__global__ __launch_bounds__(256, 4) void k_router(
    const float* __restrict__ x,
    const float* __restrict__ gate_w, const float* __restrict__ cls_w,
    const float* __restrict__ escale, const float* __restrict__ ebias,
    int* __restrict__ cnt, int* __restrict__ etok, float* __restrict__ ew,
    unsigned short* __restrict__ xb) {
    const int lane = threadIdx.x & 63;
    const int tok = blockIdx.x * 4 + (threadIdx.x >> 6);
    const float* xr = x + (size_t)tok * HID + lane * 4;
    float4 xv[8];
#pragma unroll
    for (int i = 0; i < 8; i++) xv[i] = *(const float4*)(xr + i * 256);
    unsigned short* xbr = xb + (size_t)tok * HID + lane * 4;
#pragma unroll
    for (int i = 0; i < 8; i++) {
        ushort4 v;
        v.x = f2bf(xv[i].x); v.y = f2bf(xv[i].y);
        v.z = f2bf(xv[i].z); v.w = f2bf(xv[i].w);
        *(ushort4*)(xbr + i * 256) = v;
    }

    float sc[NEXP];
    float mx = 0.f;
#pragma unroll
    for (int e = 0; e < NEXP; e++) {
        const float* cw = cls_w + (size_t)e * HID + lane * 4;
        const float* gw = gate_w + (size_t)e * HID + lane * 4;
        float pc = 0.f, pg = 0.f;
        {
            float4 cv[8];
#pragma unroll
            for (int i = 0; i < 8; i++) cv[i] = *(const float4*)(cw + i * 256);
#pragma unroll
            for (int i = 0; i < 8; i++) {
                pc = fmaf(xv[i].x, cv[i].x, pc);
                pc = fmaf(xv[i].y, cv[i].y, pc);
                pc = fmaf(xv[i].z, cv[i].z, pc);
                pc = fmaf(xv[i].w, cv[i].w, pc);
            }
        }
        {
            float4 gv[8];
#pragma unroll
            for (int i = 0; i < 8; i++) gv[i] = *(const float4*)(gw + i * 256);
#pragma unroll
            for (int i = 0; i < 8; i++) {
                pg = fmaf(xv[i].x, gv[i].x, pg);
                pg = fmaf(xv[i].y, gv[i].y, pg);
                pg = fmaf(xv[i].z, gv[i].z, pg);
                pg = fmaf(xv[i].w, gv[i].w, pg);
            }
        }
#pragma unroll
        for (int o = 32; o >= 1; o >>= 1) {
            pc += __shfl_xor(pc, o);
            pg += __shfl_xor(pg, o);
        }
        float lg = pc * (pg / (1.f + __expf(-pg)));
        sc[e] = fabsf(lg);
        mx = fmaxf(mx, sc[e]);
    }
    float s = 0.f;
#pragma unroll
    for (int e = 0; e < NEXP; e++) { sc[e] = __expf(sc[e] - mx); s += sc[e]; }
    float inv = 1.f / s;
    int i1 = -1, i2 = -1;
    float b1 = -1e30f, b2 = -1e30f, v1 = 0.f, v2 = 0.f;
#pragma unroll
    for (int e = 0; e < NEXP; e++) {
        float sv = sc[e] * inv;
        float b = sv + ebias[e];
        if (b > b1) { b2 = b1; i2 = i1; v2 = v1; b1 = b; i1 = e; v1 = sv; }
        else if (b > b2) { b2 = b; i2 = e; v2 = sv; }
    }
    if (lane == 0) {
        float w1 = 1.f + v1 * escale[i1];
        float w2 = 1.f + v2 * escale[i2];
        int p1 = atomicAdd(&cnt[i1], 1);
        etok[i1 * TTOK + p1] = tok * 2;     ew[i1 * TTOK + p1] = w1;
        int p2 = atomicAdd(&cnt[i2], 1);
        etok[i2 * TTOK + p2] = tok * 2 + 1; ew[i2 * TTOK + p2] = w2;
    }
}

__global__ void k_offsets(const int* __restrict__ cnt, int* __restrict__ offs) {
    if (threadIdx.x == 0) {
        int a = 0;
        for (int e = 0; e < NEXP; e++) { offs[e] = a; a += cnt[e]; }
    }
}

// Gate+up GEMM (R9-proven). BM=384, BN=64(G)+64(U), BK=64, 1024 thr / 16 waves.
// A: dbuf via global_load_lds. B: fp32 -> bf16 reg-carried one iter (no w2b pass).
__global__ __launch_bounds__(1024, 4) void k_glu16(
    const unsigned short* __restrict__ xb,
    const float* __restrict__ wg, const float* __restrict__ wu,
    const float* __restrict__ sg, const float* __restrict__ su,
    unsigned short* __restrict__ abuf, unsigned short* __restrict__ hbuf,
    const int* __restrict__ cnt, const int* __restrict__ offs,
    const int* __restrict__ etok) {
    __shared__ alignas(16) unsigned short sA[2][BM * BK];   // 2 x 48 KB
    __shared__ alignas(16) unsigned short sBg[64 * BK];     // 8 KB
    __shared__ alignas(16) unsigned short sBu[64 * BK];     // 8 KB

    const int bx = blockIdx.x, t = threadIdx.x;
    const int lane = t & 63, w = t >> 6;
    const int wm = w >> 1, wn = w & 1;
    const int fr = lane & 15, fo = lane >> 4;

    const bool routed = bx >= GLU_SH;
    int n0, m_start, m_stop, obase, Ntot;
    const float *Bg, *Bu;
    unsigned short* outp;
    const int* etk = nullptr;
    if (routed) {
        int rx = bx - GLU_SH;
        int e = rx / 22; n0 = (rx % 22) * 64;
        int M = cnt[e];
        if (M <= 0) return;
        m_start = 0; m_stop = M; obase = offs[e]; Ntot = INTER;
        Bg = wg + ((size_t)e * INTER + n0) * HID;
        Bu = wu + ((size_t)e * INTER + n0) * HID;
        outp = abuf; etk = etok + e * TTOK;
    } else {
        n0 = (bx / 6) * 64;
        m_start = (bx % 6) * BM; m_stop = min(TTOK, m_start + BM);
        obase = 0; Ntot = SINTER;
        Bg = sg + (size_t)n0 * HID;
        Bu = su + (size_t)n0 * HID;
        outp = hbuf;
    }

    const int brow = t >> 4, bc4 = (t & 15) * 4;
    const float* srcG = Bg + (size_t)brow * HID + bc4;
    const float* srcU = Bu + (size_t)brow * HID + bc4;
    const unsigned wBo = swz((unsigned)(brow * 128 + bc4 * 2));

    unsigned aoff[3][2], boff[2][2];
#pragma unroll
    for (int mi = 0; mi < 3; mi++)
#pragma unroll
        for (int ks = 0; ks < 2; ks++)
            aoff[mi][ks] = swz((unsigned)((wm * 48 + mi * 16 + fr) * 128 + ks * 64 + fo * 16));
#pragma unroll
    for (int nj = 0; nj < 2; nj++)
#pragma unroll
        for (int ks = 0; ks < 2; ks++)
            boff[nj][ks] = swz((unsigned)((wn * 32 + nj * 16 + fr) * 128 + ks * 64 + fo * 16));

    const int arow_off = lane >> 3;
    const int achunk = (lane & 7) ^ arow_off;

    for (int m0 = m_start; m0 < m_stop; m0 += BM) {
        const int rv = min(m_stop - m0, BM);
        const unsigned short* srcA[3];
#pragma unroll
        for (int j = 0; j < 3; j++) {
            int r = (w * 3 + j) * 8 + arow_off;
            int rr = r < rv ? r : rv - 1;
            int tok = routed ? (etk[m0 + rr] >> 1) : (m0 + rr);
            srcA[j] = xb + (size_t)tok * HID + achunk * 8;
        }

        f32x4 ag[3][2], au[3][2];
#pragma unroll
        for (int mi = 0; mi < 3; mi++)
#pragma unroll
            for (int nj = 0; nj < 2; nj++) { ag[mi][nj] = {0.f,0.f,0.f,0.f}; au[mi][nj] = {0.f,0.f,0.f,0.f}; }

        // prologue: A(0) -> buf0, B(0) -> regs
#pragma unroll
        for (int j = 0; j < 3; j++)
            gload16(srcA[j], (char*)sA + (w * 3 + j) * 1024);
        float4 gC = *(const float4*)(srcG);
        float4 uC = *(const float4*)(srcU);
        float4 gN, uN;

        for (int kk = 0; kk < HID / BK; ++kk) {
            const int cur = kk & 1;
            bsync();                       // all waves done reading LDS of iter kk-1
            if (kk + 1 < HID / BK) {       // issue prefetch of (kk+1)
                const int k0n = (kk + 1) * BK;
#pragma unroll
                for (int j = 0; j < 3; j++)
                    gload16(srcA[j] + k0n, (char*)sA + (cur ^ 1) * (BM * BK * 2) + (w * 3 + j) * 1024);
                gN = *(const float4*)(srcG + k0n);
                uN = *(const float4*)(srcU + k0n);
            }
            __builtin_amdgcn_sched_barrier(0);
            {   // ds_write B(kk); compiler's auto-wait is counted (prefetch stays in flight)
                ushort4 vg, vu;
                vg.x = f2bf(gC.x); vg.y = f2bf(gC.y); vg.z = f2bf(gC.z); vg.w = f2bf(gC.w);
                vu.x = f2bf(uC.x); vu.y = f2bf(uC.y); vu.z = f2bf(uC.z); vu.w = f2bf(uC.w);
                *(ushort4*)((char*)sBg + wBo) = vg;
                *(ushort4*)((char*)sBu + wBo) = vu;
            }
            WAIT_LGKM0;
            bsync();                       // A(kk) + B(kk) visible to all waves
            const char* sAc = (const char*)sA + cur * (BM * BK * 2);
#pragma unroll
            for (int ks = 0; ks < 2; ++ks) {
                bf16x8 af[3], gf[2], uf[2];
#pragma unroll
                for (int mi = 0; mi < 3; mi++) af[mi] = *(const bf16x8*)(sAc + aoff[mi][ks]);
#pragma unroll
                for (int nj = 0; nj < 2; nj++) {
                    gf[nj] = *(const bf16x8*)((const char*)sBg + boff[nj][ks]);
                    uf[nj] = *(const bf16x8*)((const char*)sBu + boff[nj][ks]);
                }
#pragma unroll
                for (int mi = 0; mi < 3; mi++)
#pragma unroll
                    for (int nj = 0; nj < 2; nj++) {
                        ag[mi][nj] = __builtin_amdgcn_mfma_f32_16x16x32_bf16(af[mi], gf[nj], ag[mi][nj], 0, 0, 0);
                        au[mi][nj] = __builtin_amdgcn_mfma_f32_16x16x32_bf16(af[mi], uf[nj], au[mi][nj], 0, 0, 0);
                    }
            }
            gC = gN; uC = uN;
        }

        // epilogue: h = silu(g)*u -> stage bf16 [384][64] in buf0 -> coalesced sweep
        char* sH = (char*)sA;              // last MFMA read buf1 (kk=31)
#pragma unroll
        for (int mi = 0; mi < 3; mi++)
#pragma unroll
            for (int jj = 0; jj < 4; jj++) {
                int r = wm * 48 + mi * 16 + fo * 4 + jj;
#pragma unroll
                for (int nj = 0; nj < 2; nj++) {
                    int c = wn * 32 + nj * 16 + fr;
                    float g = ag[mi][nj][jj];
                    float u = au[mi][nj][jj];
                    float h = (g / (1.f + __expf(-g))) * u;
                    *(unsigned short*)(sH + swz((unsigned)(r * 128 + c * 2))) = f2bf(h);
                }
            }
        WAIT_LGKM0;
        bsync();
#pragma unroll
        for (int q = 0; q < 3; q++) {
            int idx = q * 1024 + t;
            int r = idx >> 3, c = idx & 7;
            if (r < rv) {
                uint4 v = *(const uint4*)(sH + swz((unsigned)(r * 128 + c * 16)));
                *(uint4*)(outp + (size_t)(obase + m0 + r) * Ntot + n0 + c * 8) = v;
            }
        }
        bsync();
    }
}

// Down GEMM (R9-proven). BM=384, BN=128, BK=64, 1024 thr / 16 waves.
__global__ __launch_bounds__(1024, 4) void k_down16(
    const unsigned short* __restrict__ abuf, const unsigned short* __restrict__ hbuf,
    const float* __restrict__ wd, const float* __restrict__ sd,
    unsigned short* __restrict__ slots,
    const int* __restrict__ cnt, const int* __restrict__ offs,
    const int* __restrict__ etok, const float* __restrict__ ew) {
    __shared__ alignas(16) unsigned short sA[2][BM * BK];   // 2 x 48 KB
    __shared__ alignas(16) unsigned short sB[128 * BK];     // 16 KB

    const int bx = blockIdx.x, t = threadIdx.x;
    const int lane = t & 63, w = t >> 6;
    const int wm = w >> 1, wn = w & 1;
    const int fr = lane & 15, fo = lane >> 4;

    const bool routed = bx >= DWN_SH;
    int n0, m_start, m_stop, K, KT;
    const float* W;
    const unsigned short* Abuf;
    size_t arow0 = 0;
    const int* etk = nullptr; const float* ewe = nullptr;
    if (routed) {
        int rx = bx - DWN_SH;
        int e = rx / 16; n0 = (rx % 16) * 128;
        int M = cnt[e];
        if (M <= 0) return;
        m_start = 0; m_stop = M;
        K = INTER; KT = INTER / BK;
        W = wd + (size_t)e * HID * INTER + (size_t)n0 * INTER;
        Abuf = abuf; arow0 = offs[e];
        etk = etok + e * TTOK; ewe = ew + e * TTOK;
    } else {
        n0 = (bx / 6) * 128;
        m_start = (bx % 6) * BM; m_stop = min(TTOK, m_start + BM);
        K = SINTER; KT = SINTER / BK;
        W = sd + (size_t)n0 * SINTER;
        Abuf = hbuf;
    }

    const int brow = t >> 3, bc8 = (t & 7) * 8;
    const float* srcB = W + (size_t)brow * K + bc8;
    const unsigned wBo = swz((unsigned)(brow * 128 + bc8 * 2));

    unsigned aoff[3][2], boff[4][2];
#pragma unroll
    for (int mi = 0; mi < 3; mi++)
#pragma unroll
        for (int ks = 0; ks < 2; ks++)
            aoff[mi][ks] = swz((unsigned)((wm * 48 + mi * 16 + fr) * 128 + ks * 64 + fo * 16));
#pragma unroll
    for (int nj = 0; nj < 4; nj++)
#pragma unroll
        for (int ks = 0; ks < 2; ks++)
            boff[nj][ks] = swz((unsigned)((wn * 64 + nj * 16 + fr) * 128 + ks * 64 + fo * 16));

    const int arow_off = lane >> 3;
    const int achunk = (lane & 7) ^ arow_off;

    for (int m0 = m_start; m0 < m_stop; m0 += BM) {
        const int rv = min(m_stop - m0, BM);
        const unsigned short* srcA[3];
#pragma unroll
        for (int j = 0; j < 3; j++) {
            int r = (w * 3 + j) * 8 + arow_off;
            int rr = r < rv ? r : rv - 1;
            srcA[j] = Abuf + (arow0 + m0 + rr) * (size_t)K + achunk * 8;
        }

        f32x4 ac[3][4];
#pragma unroll
        for (int mi = 0; mi < 3; mi++)
#pragma unroll
            for (int nj = 0; nj < 4; nj++) ac[mi][nj] = {0.f, 0.f, 0.f, 0.f};

#pragma unroll
        for (int j = 0; j < 3; j++)
            gload16(srcA[j], (char*)sA + (w * 3 + j) * 1024);
        float4 bC0 = *(const float4*)(srcB), bC1 = *(const float4*)(srcB + 4);
        float4 bN0, bN1;

        for (int kk = 0; kk < KT; ++kk) {
            const int cur = kk & 1;
            bsync();
            if (kk + 1 < KT) {
                const int k0n = (kk + 1) * BK;
#pragma unroll
                for (int j = 0; j < 3; j++)
                    gload16(srcA[j] + k0n, (char*)sA + (cur ^ 1) * (BM * BK * 2) + (w * 3 + j) * 1024);
                bN0 = *(const float4*)(srcB + k0n);
                bN1 = *(const float4*)(srcB + k0n + 4);
            }
            __builtin_amdgcn_sched_barrier(0);
            {
                bf16x8 v;
                v[0]=(short)f2bf(bC0.x); v[1]=(short)f2bf(bC0.y); v[2]=(short)f2bf(bC0.z); v[3]=(short)f2bf(bC0.w);
                v[4]=(short)f2bf(bC1.x); v[5]=(short)f2bf(bC1.y); v[6]=(short)f2bf(bC1.z); v[7]=(short)f2bf(bC1.w);
                *(bf16x8*)((char*)sB + wBo) = v;
            }
            WAIT_LGKM0;
            bsync();
            const char* sAc = (const char*)sA + cur * (BM * BK * 2);
#pragma unroll
            for (int ks = 0; ks < 2; ++ks) {
                bf16x8 af[3], bf[4];
#pragma unroll
                for (int mi = 0; mi < 3; mi++) af[mi] = *(const bf16x8*)(sAc + aoff[mi][ks]);
#pragma unroll
                for (int nj = 0; nj < 4; nj++) bf[nj] = *(const bf16x8*)((const char*)sB + boff[nj][ks]);
#pragma unroll
                for (int mi = 0; mi < 3; mi++)
#pragma unroll
                    for (int nj = 0; nj < 4; nj++)
                        ac[mi][nj] = __builtin_amdgcn_mfma_f32_16x16x32_bf16(af[mi], bf[nj], ac[mi][nj], 0, 0, 0);
            }
            bC0 = bN0; bC1 = bN1;
        }

        // epilogue: two 64-col passes staged into buf0 (KT even -> last MFMA read buf1)
        char* sH = (char*)sA;
#pragma unroll
        for (int p = 0; p < 2; p++) {
            if (wn == p) {
#pragma unroll
                for (int mi = 0; mi < 3; mi++)
#pragma unroll
                    for (int jj = 0; jj < 4; jj++) {
                        int r = wm * 48 + mi * 16 + fo * 4 + jj;
                        float wt = 1.f;
                        if (routed) wt = (r < rv) ? ewe[m0 + r] : 0.f;
#pragma unroll
                        for (int nj = 0; nj < 4; nj++) {
                            int c = nj * 16 + fr;
                            *(unsigned short*)(sH + swz((unsigned)(r * 128 + c * 2))) =
                                f2bf(ac[mi][nj][jj] * wt);
                        }
                    }
            }
            WAIT_LGKM0;
            bsync();
#pragma unroll
            for (int q = 0; q < 3; q++) {
                int idx = q * 1024 + t;
                int r = idx >> 3, c = idx & 7;
                if (r < rv) {
                    uint4 v = *(const uint4*)(sH + swz((unsigned)(r * 128 + c * 16)));
                    int tok, slice;
                    if (routed) { int entry = etk[m0 + r]; tok = entry >> 1; slice = entry & 1; }
                    else        { tok = m0 + r; slice = 2; }
                    *(uint4*)(slots + ((size_t)slice * TTOK + tok) * HID + n0 + p * 64 + c * 8) = v;
                }
            }
            bsync();
        }
    }
}

__global__ __launch_bounds__(256) void k_final(float* __restrict__ out,
                                               const unsigned short* __restrict__ slots) {
    size_t i = ((size_t)blockIdx.x * 256 + threadIdx.x) * 8;
    u16x8 s0 = *(const u16x8*)(slots + i);
    u16x8 s1 = *(const u16x8*)(slots + (size_t)TTOK * HID + i);
    u16x8 s2 = *(const u16x8*)(slots + (size_t)2 * TTOK * HID + i);
    float4 o0, o1;
    o0.x = bf2f(s0[0]) + bf2f(s1[0]) + bf2f(s2[0]);
    o0.y = bf2f(s0[1]) + bf2f(s1[1]) + bf2f(s2[1]);
    o0.z = bf2f(s0[2]) + bf2f(s1[2]) + bf2f(s2[2]);
    o0.w = bf2f(s0[3]) + bf2f(s1[3]) + bf2f(s2[3]);
    o1.x = bf2f(s0[4]) + bf2f(s1[4]) + bf2f(s2[4]);
    o1.y = bf2f(s0[5]) + bf2f(s1[5]) + bf2f(s2[5]);
    o1.z = bf2f(s0[6]) + bf2f(s1[6]) + bf2f(s2[6]);
    o1.w = bf2f(s0[7]) + bf2f(s1[7]) + bf2f(s2[7]);
    *(float4*)(out + i) = o0;
    *(float4*)(out + i + 4) = o1;
}

extern "C" void kernel_launch(void* const* d_in, const int* in_sizes, int n_in,
                              void* d_out, int out_size, void* d_ws, size_t ws_size,
                              hipStream_t stream) {
    const float* x = (const float*)d_in[0];
    const float* gate_w = (const float*)d_in[1];
    const float* cls_w = (const float*)d_in[2];
    const float* escale = (const float*)d_in[3];
    const float* ebias = (const float*)d_in[4];
    const float* wg = (const float*)d_in[5];
    const float* wu = (const float*)d_in[6];
    const float* wd = (const float*)d_in[7];
    const float* sg = (const float*)d_in[8];
    const float* su = (const float*)d_in[9];
    const float* sd = (const float*)d_in[10];
    float* out = (float*)d_out;

    char* ws = (char*)d_ws;
    size_t o = 0;
    auto alloc = [&](size_t bytes) {
        char* p = ws + o;
        o += (bytes + 255) & ~(size_t)255;
        return p;
    };
    unsigned short* xb    = (unsigned short*)alloc((size_t)TTOK * HID * 2);
    unsigned short* hbuf  = (unsigned short*)alloc((size_t)TTOK * SINTER * 2);
    unsigned short* abuf  = (unsigned short*)alloc((size_t)2 * TTOK * INTER * 2);
    unsigned short* slots = (unsigned short*)alloc((size_t)3 * TTOK * HID * 2);
    int* cnt              = (int*)alloc(256);
    int* offs             = (int*)alloc(256);
    int* etok             = (int*)alloc((size_t)NEXP * TTOK * 4);
    float* ew             = (float*)alloc((size_t)NEXP * TTOK * 4);

    k_zero<<<1, 64, 0, stream>>>(cnt);
    k_router<<<512, 256, 0, stream>>>(x, gate_w, cls_w, escale, ebias, cnt, etok, ew, xb);
    k_offsets<<<1, 64, 0, stream>>>(cnt, offs);
    k_glu16<<<GLU_SH + GLU_RT, 1024, 0, stream>>>(
        xb, wg, wu, sg, su, abuf, hbuf, cnt, offs, etok);
    k_down16<<<DWN_SH + DWN_RT, 1024, 0, stream>>>(
        abuf, hbuf, wd, sd, slots, cnt, offs, etok, ew);
    k_final<<<2048, 256, 0, stream>>>(out, slots);
}